// Round 11
// baseline (274.705 us; speedup 1.0000x reference)
//
#include <hip/hip_runtime.h>
#include <hip/hip_bf16.h>

typedef short bf16x8 __attribute__((ext_vector_type(8)));
typedef float f32x4 __attribute__((ext_vector_type(4)));
#define MFMA16 __builtin_amdgcn_mfma_f32_16x16x32_bf16

// ---- split-bf16 helpers -----------------------------------------------------
__device__ __forceinline__ unsigned short rne_bf16(float f) {
  unsigned u = __builtin_bit_cast(unsigned, f);
  return (unsigned short)((u + 0x7fffu + ((u >> 16) & 1u)) >> 16);
}
__device__ __forceinline__ float bf16f(unsigned short h) {
  unsigned u = ((unsigned)h) << 16;
  return __builtin_bit_cast(float, u);
}
__device__ __forceinline__ void split2(float f, short& h, short& l) {
  unsigned short hh = rne_bf16(f);
  h = (short)hh;
  l = (short)rne_bf16(f - bf16f(hh));
}

// ---- ws layout --------------------------------------------------------------
constexpr int NW_SH = 32768;   // node_W  256x128
constexpr int WC_SH = 16384;   // WcEt    128x128
constexpr int GF_SH = 65536;   // gfcn    128x512
constexpr int OFF_NWH = 0;
constexpr int OFF_NWL = NW_SH;
constexpr int OFF_WCH = 2 * NW_SH;
constexpr int OFF_WCL = 2 * NW_SH + WC_SH;
constexpr int OFF_GFH = 2 * NW_SH + 2 * WC_SH;
constexpr int OFF_GFL = 2 * NW_SH + 2 * WC_SH + GF_SH;
constexpr size_t OFF_BIAS_BYTES = (size_t)(2 * NW_SH + 2 * WC_SH + 2 * GF_SH) * 2; // 458752
constexpr size_t OFF_VF_BYTES = OFF_BIAS_BYTES + 6 * 128 * 4;                      // 461824
constexpr int NT_MAX = 2048;                    // B/16
constexpr int VF_SH = NT_MAX * 4 * 4 * 64 * 8;  // 16777216 shorts per plane
constexpr size_t WS_NEED = OFF_VF_BYTES + (size_t)2 * (size_t)VF_SH * 2;           // ~67.6 MB

// ---- setup: pack weights into MFMA fragment layout (hi/lo bf16 planes) ------
__global__ __launch_bounds__(256) void setup_kernel(
    const float* __restrict__ node_W, const float* __restrict__ conv_W,
    const float* __restrict__ gfcn_W, const float* __restrict__ role_emb,
    const float* __restrict__ conv_b, const float* __restrict__ bn_gamma,
    const float* __restrict__ bn_beta, const float* __restrict__ bn_mean,
    const float* __restrict__ bn_var, short* __restrict__ wsS,
    float* __restrict__ bias_af) {
  int idx = blockIdx.x * 256 + threadIdx.x;
  int stride = gridDim.x * 256;
  for (int i = idx; i < 115456; i += stride) {
    if (i < 114688) {
      int j = i & 7, lane = (i >> 3) & 63;
      int kq = ((lane >> 4) & 3) * 8 + j, n16 = lane & 15;
      float val;
      short *ph, *pl;
      int loc;
      if (i < NW_SH) {
        loc = i;
        int f = i >> 9, kf = f & 7, nfr = f >> 3;
        int k = kf * 32 + kq, n = nfr * 16 + n16;
        val = node_W[k * 128 + n];
        ph = wsS + OFF_NWH; pl = wsS + OFF_NWL;
      } else if (i < NW_SH + WC_SH) {
        loc = i - NW_SH;
        int f = loc >> 9, kf = f & 3, nfr = f >> 2;
        int k = kf * 32 + kq, n = nfr * 16 + n16;
        float s = bn_gamma[n] * rsqrtf(bn_var[n] + 1e-5f);
        val = s * conv_W[n * 256 + 128 + k];     // WcEt[e=k][f=n]
        ph = wsS + OFF_WCH; pl = wsS + OFF_WCL;
      } else {
        loc = i - NW_SH - WC_SH;
        int f = loc >> 9, kf = f & 3, nfr = f >> 2;   // nfr 0..31
        int k = kf * 32 + kq, n = nfr * 16 + n16;     // n 0..511
        val = (n < 256) ? gfcn_W[k * 256 + n]
                        : gfcn_W[(128 + k) * 256 + (n - 256)];
        ph = wsS + OFF_GFH; pl = wsS + OFF_GFL;
      }
      short h, l;
      split2(val, h, l);
      ph[loc] = h; pl[loc] = l;
    } else {
      int loc = i - 114688;
      int a = loc >> 7, fc = loc & 127;
      int role = (a == 5) ? 6 : a;   // ROLES = {0,1,2,3,4,6}
      float s = bn_gamma[fc] * rsqrtf(bn_var[fc] + 1e-5f);
      float dot = 0.f;
      for (int e = 0; e < 128; ++e)
        dot = fmaf(role_emb[role * 128 + e], conv_W[fc * 256 + e], dot);
      bias_af[loc] = s * (dot + conv_b[fc] - bn_mean[fc]) + bn_beta[fc];
    }
  }
}

// ---- kernel A: 2 tiles/block, cross-tile software-pipelined gather ----------
__global__ __launch_bounds__(256) void ent_kernel(
    const int* __restrict__ a_ids, const int* __restrict__ b_ids,
    const int* __restrict__ c_ids, const int* __restrict__ event_ids,
    const float* __restrict__ nf, const float* __restrict__ ent,
    const float* __restrict__ node_b, const short* __restrict__ wsS,
    short* __restrict__ vfh, short* __restrict__ vfl) {
  __shared__ __align__(16) short lhs[4][16 * 128];
  __shared__ __align__(16) short lls[4][16 * 128];
  const int t = threadIdx.x;
  const int wv = t >> 6, lane = t & 63;
  const int r15 = lane & 15, q = lane >> 4;
  const int tile0 = blockIdx.x * 2;

  const bf16x8* nwh = (const bf16x8*)(wsS + OFF_NWH);
  const bf16x8* nwl = (const bf16x8*)(wsS + OFF_NWL);

  // wave wv owns id-column wv; stack order a,event,b,c
  const int* pw = (wv == 0) ? a_ids : (wv == 1) ? event_ids
                : (wv == 2) ? b_ids : c_ids;

  // ---- both tiles' ids up front ---------------------------------------------
  int idr0 = pw[tile0 * 16 + r15];
  int idr1 = pw[(tile0 + 1) * 16 + r15];
  int eid0[4], eid1[4];
  #pragma unroll
  for (int rg = 0; rg < 4; ++rg) {
    eid0[rg] = pw[tile0 * 16 + q * 4 + rg];
    eid1[rg] = pw[(tile0 + 1) * 16 + q * 4 + rg];
  }
  const float* arow0 = nf + (size_t)idr0 * 256 + q * 8;
  const float* arow1 = nf + (size_t)idr1 * 256 + q * 8;

  // helper lambdas -----------------------------------------------------------
  auto CONV = [&](float4 (&av)[8], bf16x8 (&Fh)[4], bf16x8 (&Fl)[4]) {
    #pragma unroll
    for (int k4 = 0; k4 < 4; ++k4) {
      #pragma unroll
      for (int j = 0; j < 4; ++j) {
        short h, l;
        split2(av[2 * k4][j], h, l);
        Fh[k4][j] = h; Fl[k4][j] = l;
        split2(av[2 * k4 + 1][j], h, l);
        Fh[k4][4 + j] = h; Fl[k4][4 + j] = l;
      }
    }
  };
  auto MFMAH = [&](bf16x8 (&Fh)[4], bf16x8 (&Fl)[4], int ksb, f32x4 (&acc)[8]) {
    #pragma unroll
    for (int k4 = 0; k4 < 4; ++k4) {
      int ks = ksb + k4;
      #pragma unroll
      for (int n8 = 0; n8 < 8; ++n8) {
        bf16x8 bh = nwh[(n8 * 8 + ks) * 64 + lane];
        bf16x8 bl = nwl[(n8 * 8 + ks) * 64 + lane];
        acc[n8] = MFMA16(Fh[k4], bh, acc[n8], 0, 0, 0);
        acc[n8] = MFMA16(Fl[k4], bh, acc[n8], 0, 0, 0);
        acc[n8] = MFMA16(Fh[k4], bl, acc[n8], 0, 0, 0);
      }
    }
  };
  auto EPI = [&](int tile, f32x4 (&acc)[8], float (&ev)[32]) {
    #pragma unroll
    for (int n8 = 0; n8 < 8; ++n8) {
      int col = n8 * 16 + r15;
      float nb = node_b[col];
      #pragma unroll
      for (int rg = 0; rg < 4; ++rg) {
        float v = ev[n8 * 4 + rg] + fmaxf(acc[n8][rg] + nb, 0.f);
        short h, l; split2(v, h, l);
        int rr = q * 4 + rg;
        int si = rr * 128 + (col ^ ((rr & 7) << 3));
        lhs[wv][si] = h; lls[wv][si] = l;
      }
    }
    #pragma unroll
    for (int ks = 0; ks < 4; ++ks) {
      int k0 = ks * 32 + q * 8;
      int si = r15 * 128 + (k0 ^ ((r15 & 7) << 3));
      ((bf16x8*)vfh)[((tile * 4 + wv) * 4 + ks) * 64 + lane] =
          *(const bf16x8*)&lhs[wv][si];
      ((bf16x8*)vfl)[((tile * 4 + wv) * 4 + ks) * 64 + lane] =
          *(const bf16x8*)&lls[wv][si];
    }
  };

  float4 avC[8], avN[8];
  bf16x8 Fh[4], Fl[4];
  f32x4 acc[8];
  float ev[32];

  // ================== tile 0 ==================
  // issue H0(t0)
  #pragma unroll
  for (int ks = 0; ks < 4; ++ks) {
    avC[2 * ks]     = *(const float4*)(arow0 + ks * 32);
    avC[2 * ks + 1] = *(const float4*)(arow0 + ks * 32 + 4);
  }
  __builtin_amdgcn_sched_barrier(0);
  #pragma unroll
  for (int n8 = 0; n8 < 8; ++n8) acc[n8] = (f32x4){0.f, 0.f, 0.f, 0.f};
  CONV(avC, Fh, Fl);
  // issue H1(t0)
  #pragma unroll
  for (int ks = 0; ks < 4; ++ks) {
    avN[2 * ks]     = *(const float4*)(arow0 + (4 + ks) * 32);
    avN[2 * ks + 1] = *(const float4*)(arow0 + (4 + ks) * 32 + 4);
  }
  __builtin_amdgcn_sched_barrier(0);
  MFMAH(Fh, Fl, 0, acc);
  CONV(avN, Fh, Fl);
  // cross-tile prefetch: issue H0(t1) + ev(t0) under MFMA H1(t0)
  #pragma unroll
  for (int ks = 0; ks < 4; ++ks) {
    avC[2 * ks]     = *(const float4*)(arow1 + ks * 32);
    avC[2 * ks + 1] = *(const float4*)(arow1 + ks * 32 + 4);
  }
  #pragma unroll
  for (int n8 = 0; n8 < 8; ++n8)
    #pragma unroll
    for (int rg = 0; rg < 4; ++rg)
      ev[n8 * 4 + rg] = ent[(size_t)eid0[rg] * 128 + n8 * 16 + r15];
  __builtin_amdgcn_sched_barrier(0);
  MFMAH(Fh, Fl, 4, acc);
  EPI(tile0, acc, ev);

  // ================== tile 1 ==================
  #pragma unroll
  for (int n8 = 0; n8 < 8; ++n8) acc[n8] = (f32x4){0.f, 0.f, 0.f, 0.f};
  CONV(avC, Fh, Fl);
  // issue H1(t1)
  #pragma unroll
  for (int ks = 0; ks < 4; ++ks) {
    avN[2 * ks]     = *(const float4*)(arow1 + (4 + ks) * 32);
    avN[2 * ks + 1] = *(const float4*)(arow1 + (4 + ks) * 32 + 4);
  }
  __builtin_amdgcn_sched_barrier(0);
  MFMAH(Fh, Fl, 0, acc);
  CONV(avN, Fh, Fl);
  // issue ev(t1)
  #pragma unroll
  for (int n8 = 0; n8 < 8; ++n8)
    #pragma unroll
    for (int rg = 0; rg < 4; ++rg)
      ev[n8 * 4 + rg] = ent[(size_t)eid1[rg] * 128 + n8 * 16 + r15];
  __builtin_amdgcn_sched_barrier(0);
  MFMAH(Fh, Fl, 4, acc);
  EPI(tile0 + 1, acc, ev);
}

// ---- kernel B: stages C+D, 512 threads / 8 waves, merged-jn D ---------------
__global__ __launch_bounds__(512) void head_kernel(
    const float* __restrict__ cond, const float* __restrict__ text,
    const float* __restrict__ gfcn_b, const short* __restrict__ wsS,
    const float* __restrict__ bias_af, const short* __restrict__ vfh,
    const short* __restrict__ vfl, float* __restrict__ out) {
  __shared__ __align__(16) unsigned char smem[49152];
  short* lds_hi = (short*)smem;                 // 96x128 bf16 hi plane
  short* lds_lo = (short*)(smem + 24576);       // lo plane
  float* umin_s = (float*)smem;                 // overlay after planes dead
  constexpr int OV = 260;

  const int t = threadIdx.x;
  const int wv = t >> 6, lane = t & 63;
  const int r15 = lane & 15, q = lane >> 4;
  const int tile = blockIdx.x;
  const int b0 = tile * 16;

  const bf16x8* wch = (const bf16x8*)(wsS + OFF_WCH);
  const bf16x8* wcl = (const bf16x8*)(wsS + OFF_WCL);
  const bf16x8* gfh = (const bf16x8*)(wsS + OFF_GFH);
  const bf16x8* gfl = (const bf16x8*)(wsS + OFF_GFL);
  const bf16x8* vfh8 = (const bf16x8*)vfh;
  const bf16x8* vfl8 = (const bf16x8*)vfl;

  // ---- Phase 0: stage cond/text rows (a=4,5) into plane rows 64..95 ---------
  #pragma unroll
  for (int j = 0; j < 8; ++j) {
    int i = j * 512 + t;
    int arr = i >> 11, rem = i & 2047, r = rem >> 7, e = rem & 127;
    const float* src = arr ? text : cond;
    float v = src[(size_t)(b0 + r) * 128 + e];
    short h, l;
    split2(v, h, l);
    int row = (4 + arr) * 16 + r;
    int si = row * 128 + (e ^ ((row & 7) << 3));
    lds_hi[si] = h; lds_lo[si] = l;
  }
  __syncthreads();

  // ---- Stage C: x = relu(vals @ WcEt + bias_af); wave owns n-frag wv --------
  {
    f32x4 xacc[6];
    #pragma unroll
    for (int a = 0; a < 6; ++a) xacc[a] = (f32x4){0.f, 0.f, 0.f, 0.f};
    #pragma unroll
    for (int ks = 0; ks < 4; ++ks) {
      int k0 = ks * 32 + q * 8;
      bf16x8 bh = wch[(wv * 4 + ks) * 64 + lane];
      bf16x8 bl = wcl[(wv * 4 + ks) * 64 + lane];
      #pragma unroll
      for (int ha = 0; ha < 2; ++ha) {
        bf16x8 ah[3], al[3];
        #pragma unroll
        for (int j = 0; j < 3; ++j) {
          int a = ha * 3 + j;
          if (a < 4) {
            ah[j] = vfh8[((tile * 4 + a) * 4 + ks) * 64 + lane];
            al[j] = vfl8[((tile * 4 + a) * 4 + ks) * 64 + lane];
          } else {
            int row = a * 16 + r15;
            int si = row * 128 + (k0 ^ ((row & 7) << 3));
            ah[j] = *(const bf16x8*)&lds_hi[si];
            al[j] = *(const bf16x8*)&lds_lo[si];
          }
        }
        __builtin_amdgcn_s_setprio(1);
        #pragma unroll
        for (int j = 0; j < 3; ++j) {
          int a = ha * 3 + j;
          xacc[a] = MFMA16(ah[j], bh, xacc[a], 0, 0, 0);
          xacc[a] = MFMA16(al[j], bh, xacc[a], 0, 0, 0);
          xacc[a] = MFMA16(ah[j], bl, xacc[a], 0, 0, 0);
        }
        __builtin_amdgcn_s_setprio(0);
      }
    }
    __syncthreads();   // all cond/text plane reads done before x overwrites
    #pragma unroll
    for (int a = 0; a < 6; ++a) {
      int col = wv * 16 + r15;
      float bv = bias_af[a * 128 + col];
      #pragma unroll
      for (int rg = 0; rg < 4; ++rg) {
        float v = fmaxf(xacc[a][rg] + bv, 0.f);
        short h, l; split2(v, h, l);
        int row = a * 16 + q * 4 + rg;
        int si = row * 128 + (col ^ ((row & 7) << 3));
        lds_hi[si] = h; lds_lo[si] = l;
      }
    }
  }
  __syncthreads();

  // ---- Stage D: u/v = x @ gfcn; acc[6][4] merged, A-frag reused 12x ---------
  f32x4 acc[6][4];
  #pragma unroll
  for (int a = 0; a < 6; ++a)
    #pragma unroll
    for (int jn = 0; jn < 4; ++jn) acc[a][jn] = (f32x4){0.f, 0.f, 0.f, 0.f};
  #pragma unroll
  for (int ks = 0; ks < 4; ++ks) {
    int k0 = ks * 32 + q * 8;
    bf16x8 bh[4], bl[4];
    #pragma unroll
    for (int jn = 0; jn < 4; ++jn) {
      int nfg = wv * 4 + jn;
      bh[jn] = gfh[(nfg * 4 + ks) * 64 + lane];
      bl[jn] = gfl[(nfg * 4 + ks) * 64 + lane];
    }
    #pragma unroll
    for (int ha = 0; ha < 2; ++ha) {
      bf16x8 ah[3], al[3];
      #pragma unroll
      for (int j = 0; j < 3; ++j) {
        int row = (ha * 3 + j) * 16 + r15;
        int si = row * 128 + (k0 ^ ((row & 7) << 3));
        ah[j] = *(const bf16x8*)&lds_hi[si];
        al[j] = *(const bf16x8*)&lds_lo[si];
      }
      __builtin_amdgcn_s_setprio(1);
      #pragma unroll
      for (int jn = 0; jn < 4; ++jn) {
        #pragma unroll
        for (int j = 0; j < 3; ++j) {
          int a = ha * 3 + j;
          acc[a][jn] = MFMA16(ah[j], bh[jn], acc[a][jn], 0, 0, 0);
          acc[a][jn] = MFMA16(al[j], bh[jn], acc[a][jn], 0, 0, 0);
          acc[a][jn] = MFMA16(ah[j], bl[jn], acc[a][jn], 0, 0, 0);
        }
      }
      __builtin_amdgcn_s_setprio(0);
    }
  }
  f32x4 mreg[4];
  #pragma unroll
  for (int jn = 0; jn < 4; ++jn) {
    #pragma unroll
    for (int rg = 0; rg < 4; ++rg) {
      float mm = acc[0][jn][rg];
      #pragma unroll
      for (int a = 1; a < 6; ++a) mm = fminf(mm, acc[a][jn][rg]);
      mreg[jn][rg] = mm;
    }
  }
  __syncthreads();   // all x reads done; planes now dead

  if (wv < 4) {      // u waves: write umin to overlay
    #pragma unroll
    for (int j = 0; j < 4; ++j) {
      int colg = wv * 64 + j * 16 + r15;
      #pragma unroll
      for (int rg = 0; rg < 4; ++rg)
        umin_s[(q * 4 + rg) * OV + colg] = mreg[j][rg];
    }
  }
  __syncthreads();
  if (wv >= 4) {     // v waves: combine in-reg vmin with LDS umin, write out
    #pragma unroll
    for (int j = 0; j < 4; ++j) {
      int g = (wv - 4) * 64 + j * 16 + r15;
      float gbv = gfcn_b[g];
      #pragma unroll
      for (int rg = 0; rg < 4; ++rg) {
        int r = q * 4 + rg;
        out[(size_t)(b0 + r) * 256 + g] =
            fmaxf(umin_s[r * OV + g] + mreg[j][rg] + gbv, 0.f);
      }
    }
  }
}

// ---- fallback: fused (R5 structure, no min-wave bound) ----------------------
__global__ __launch_bounds__(256) void fused_fallback(
    const int* __restrict__ a_ids, const int* __restrict__ b_ids,
    const int* __restrict__ c_ids, const int* __restrict__ event_ids,
    const float* __restrict__ nf, const float* __restrict__ cond,
    const float* __restrict__ text, const float* __restrict__ ent,
    const float* __restrict__ node_b, const float* __restrict__ gfcn_b,
    const short* __restrict__ wsS, const float* __restrict__ bias_af,
    float* __restrict__ out) {
  __shared__ __align__(16) unsigned char smem[49152];
  short* lds_hi = (short*)smem;
  short* lds_lo = (short*)(smem + 24576);
  float* umin_s = (float*)smem;
  float* vmin_s = (float*)(smem + 16640);
  constexpr int OV = 260;

  const int t = threadIdx.x;
  const int wv = t >> 6, lane = t & 63;
  const int r15 = lane & 15, q = lane >> 4;
  const int b0 = blockIdx.x * 16;

  const bf16x8* nwh = (const bf16x8*)(wsS + OFF_NWH);
  const bf16x8* nwl = (const bf16x8*)(wsS + OFF_NWL);
  const bf16x8* wch = (const bf16x8*)(wsS + OFF_WCH);
  const bf16x8* wcl = (const bf16x8*)(wsS + OFF_WCL);
  const bf16x8* gfh = (const bf16x8*)(wsS + OFF_GFH);
  const bf16x8* gfl = (const bf16x8*)(wsS + OFF_GFL);

  const int* pw = (wv == 0) ? a_ids : (wv == 1) ? event_ids
                : (wv == 2) ? b_ids : c_ids;
  int my_id = pw[b0 + r15];
  int eid[4];
  #pragma unroll
  for (int rg = 0; rg < 4; ++rg) eid[rg] = pw[b0 + q * 4 + rg];
  const float* arow = nf + (size_t)my_id * 256 + q * 8;

  float4 avA[8];
  #pragma unroll
  for (int ks = 0; ks < 4; ++ks) {
    avA[2 * ks]     = *(const float4*)(arow + ks * 32);
    avA[2 * ks + 1] = *(const float4*)(arow + ks * 32 + 4);
  }
  #pragma unroll
  for (int j = 0; j < 16; ++j) {
    int i = j * 256 + t;
    int arr = i >> 11, rem = i & 2047, r = rem >> 7, e = rem & 127;
    const float* src = arr ? text : cond;
    float v = src[(size_t)(b0 + r) * 128 + e];
    short h, l;
    split2(v, h, l);
    int row = (4 + arr) * 16 + r;
    int si = row * 128 + (e ^ ((row & 7) << 3));
    lds_hi[si] = h; lds_lo[si] = l;
  }
  {
    f32x4 acc[8];
    #pragma unroll
    for (int n8 = 0; n8 < 8; ++n8) acc[n8] = (f32x4){0.f, 0.f, 0.f, 0.f};
    float4 avB[8];
    #pragma unroll
    for (int ks = 0; ks < 4; ++ks) {
      avB[2 * ks]     = *(const float4*)(arow + (4 + ks) * 32);
      avB[2 * ks + 1] = *(const float4*)(arow + (4 + ks) * 32 + 4);
    }
    #pragma unroll
    for (int ks = 0; ks < 8; ++ks) {
      bf16x8 ah, al;
      {
        float4 v0 = (ks < 4) ? avA[2 * ks] : avB[2 * (ks - 4)];
        float4 v1 = (ks < 4) ? avA[2 * ks + 1] : avB[2 * (ks - 4) + 1];
        #pragma unroll
        for (int j = 0; j < 4; ++j) {
          short h, l;
          split2(v0[j], h, l);
          ah[j] = h; al[j] = l;
          split2(v1[j], h, l);
          ah[4 + j] = h; al[4 + j] = l;
        }
      }
      #pragma unroll
      for (int n8 = 0; n8 < 8; ++n8) {
        bf16x8 bh = nwh[(n8 * 8 + ks) * 64 + lane];
        bf16x8 bl = nwl[(n8 * 8 + ks) * 64 + lane];
        acc[n8] = MFMA16(ah, bh, acc[n8], 0, 0, 0);
        acc[n8] = MFMA16(al, bh, acc[n8], 0, 0, 0);
        acc[n8] = MFMA16(ah, bl, acc[n8], 0, 0, 0);
      }
    }
    float ev[32];
    #pragma unroll
    for (int n8 = 0; n8 < 8; ++n8)
      #pragma unroll
      for (int rg = 0; rg < 4; ++rg)
        ev[n8 * 4 + rg] = ent[(size_t)eid[rg] * 128 + n8 * 16 + r15];
    #pragma unroll
    for (int n8 = 0; n8 < 8; ++n8) {
      int col = n8 * 16 + r15;
      float nb = node_b[col];
      #pragma unroll
      for (int rg = 0; rg < 4; ++rg) {
        float v = ev[n8 * 4 + rg] + fmaxf(acc[n8][rg] + nb, 0.f);
        short h, l; split2(v, h, l);
        int row = wv * 16 + q * 4 + rg;
        int si = row * 128 + (col ^ ((row & 7) << 3));
        lds_hi[si] = h; lds_lo[si] = l;
      }
    }
  }
  __syncthreads();
  {
    f32x4 xacc[6][2];
    #pragma unroll
    for (int a = 0; a < 6; ++a) {
      xacc[a][0] = (f32x4){0.f, 0.f, 0.f, 0.f};
      xacc[a][1] = (f32x4){0.f, 0.f, 0.f, 0.f};
    }
    #pragma unroll
    for (int ks = 0; ks < 4; ++ks) {
      int k0 = ks * 32 + q * 8;
      #pragma unroll
      for (int ha = 0; ha < 2; ++ha) {
        bf16x8 ah[3], al[3];
        #pragma unroll
        for (int j = 0; j < 3; ++j) {
          int row = (ha * 3 + j) * 16 + r15;
          int si = row * 128 + (k0 ^ ((row & 7) << 3));
          ah[j] = *(const bf16x8*)&lds_hi[si];
          al[j] = *(const bf16x8*)&lds_lo[si];
        }
        #pragma unroll
        for (int jn = 0; jn < 2; ++jn) {
          bf16x8 bh = wch[((wv * 2 + jn) * 4 + ks) * 64 + lane];
          bf16x8 bl = wcl[((wv * 2 + jn) * 4 + ks) * 64 + lane];
          #pragma unroll
          for (int j = 0; j < 3; ++j) {
            int a = ha * 3 + j;
            xacc[a][jn] = MFMA16(ah[j], bh, xacc[a][jn], 0, 0, 0);
            xacc[a][jn] = MFMA16(al[j], bh, xacc[a][jn], 0, 0, 0);
            xacc[a][jn] = MFMA16(ah[j], bl, xacc[a][jn], 0, 0, 0);
          }
        }
      }
    }
    __syncthreads();
    #pragma unroll
    for (int a = 0; a < 6; ++a) {
      #pragma unroll
      for (int jn = 0; jn < 2; ++jn) {
        int col = (wv * 2 + jn) * 16 + r15;
        float bv = bias_af[a * 128 + col];
        #pragma unroll
        for (int rg = 0; rg < 4; ++rg) {
          float v = fmaxf(xacc[a][jn][rg] + bv, 0.f);
          short h, l; split2(v, h, l);
          int row = a * 16 + q * 4 + rg;
          int si = row * 128 + (col ^ ((row & 7) << 3));
          lds_hi[si] = h; lds_lo[si] = l;
        }
      }
    }
  }
  __syncthreads();
  f32x4 mreg[8];
  #pragma unroll
  for (int grp = 0; grp < 4; ++grp) {
    f32x4 acc[6][2];
    #pragma unroll
    for (int a = 0; a < 6; ++a) {
      acc[a][0] = (f32x4){0.f, 0.f, 0.f, 0.f};
      acc[a][1] = (f32x4){0.f, 0.f, 0.f, 0.f};
    }
    #pragma unroll
    for (int ks = 0; ks < 4; ++ks) {
      int k0 = ks * 32 + q * 8;
      #pragma unroll
      for (int ha = 0; ha < 2; ++ha) {
        bf16x8 ah[3], al[3];
        #pragma unroll
        for (int j = 0; j < 3; ++j) {
          int row = (ha * 3 + j) * 16 + r15;
          int si = row * 128 + (k0 ^ ((row & 7) << 3));
          ah[j] = *(const bf16x8*)&lds_hi[si];
          al[j] = *(const bf16x8*)&lds_lo[si];
        }
        #pragma unroll
        for (int jn = 0; jn < 2; ++jn) {
          int nfg = wv * 8 + grp * 2 + jn;
          bf16x8 bh = gfh[(nfg * 4 + ks) * 64 + lane];
          bf16x8 bl = gfl[(nfg * 4 + ks) * 64 + lane];
          #pragma unroll
          for (int j = 0; j < 3; ++j) {
            int a = ha * 3 + j;
            acc[a][jn] = MFMA16(ah[j], bh, acc[a][jn], 0, 0, 0);
            acc[a][jn] = MFMA16(al[j], bh, acc[a][jn], 0, 0, 0);
            acc[a][jn] = MFMA16(ah[j], bl, acc[a][jn], 0, 0, 0);
          }
        }
      }
    }
    #pragma unroll
    for (int jn = 0; jn < 2; ++jn) {
      #pragma unroll
      for (int rg = 0; rg < 4; ++rg) {
        float mm = acc[0][jn][rg];
        #pragma unroll
        for (int a = 1; a < 6; ++a) mm = fminf(mm, acc[a][jn][rg]);
        mreg[grp * 2 + jn][rg] = mm;
      }
    }
  }
  __syncthreads();
  {
    float* dst = (wv >= 2) ? vmin_s : umin_s;
    int cbase = (wv & 1) * 128;
    #pragma unroll
    for (int j = 0; j < 8; ++j) {
      int colg = cbase + j * 16 + r15;
      #pragma unroll
      for (int rg = 0; rg < 4; ++rg)
        dst[(q * 4 + rg) * OV + colg] = mreg[j][rg];
    }
  }
  __syncthreads();
  #pragma unroll
  for (int j = 0; j < 16; ++j) {
    int i = j * 256 + t;
    int r = i >> 8, g = i & 255;
    out[(size_t)(b0 + r) * 256 + g] =
        fmaxf(umin_s[r * OV + g] + vmin_s[r * OV + g] + gfcn_b[g], 0.f);
  }
}

extern "C" void kernel_launch(void* const* d_in, const int* in_sizes, int n_in,
                              void* d_out, int out_size, void* d_ws, size_t ws_size,
                              hipStream_t stream) {
  const int* a_ids = (const int*)d_in[0];
  const int* b_ids = (const int*)d_in[1];
  const int* c_ids = (const int*)d_in[2];
  const int* event_ids = (const int*)d_in[3];
  const float* node_features = (const float*)d_in[4];
  const float* cond_rel = (const float*)d_in[5];
  const float* text = (const float*)d_in[6];
  const float* entity_emb = (const float*)d_in[7];
  const float* role_emb = (const float*)d_in[8];
  const float* node_W = (const float*)d_in[9];
  const float* node_b = (const float*)d_in[10];
  const float* conv_W = (const float*)d_in[11];
  const float* conv_b = (const float*)d_in[12];
  const float* bn_gamma = (const float*)d_in[13];
  const float* bn_beta = (const float*)d_in[14];
  const float* bn_mean = (const float*)d_in[15];
  const float* bn_var = (const float*)d_in[16];
  const float* gfcn_W = (const float*)d_in[17];
  const float* gfcn_b = (const float*)d_in[18];
  float* out = (float*)d_out;

  short* wsS = (short*)d_ws;
  float* bias_af = (float*)((char*)d_ws + OFF_BIAS_BYTES);
  const int B = in_sizes[0];   // 32768
  const int NT = B / 16;       // 2048

  setup_kernel<<<452, 256, 0, stream>>>(node_W, conv_W, gfcn_W, role_emb,
                                        conv_b, bn_gamma, bn_beta, bn_mean,
                                        bn_var, wsS, bias_af);
  if (ws_size >= WS_NEED && NT <= NT_MAX && (NT % 2) == 0) {
    short* vfh = (short*)((char*)d_ws + OFF_VF_BYTES);
    short* vfl = vfh + VF_SH;
    ent_kernel<<<NT / 2, 256, 0, stream>>>(a_ids, b_ids, c_ids, event_ids,
                                           node_features, entity_emb, node_b,
                                           wsS, vfh, vfl);
    head_kernel<<<NT, 512, 0, stream>>>(cond_rel, text, gfcn_b, wsS, bias_af,
                                        vfh, vfl, out);
  } else {
    fused_fallback<<<NT, 256, 0, stream>>>(
        a_ids, b_ids, c_ids, event_ids, node_features, cond_rel, text,
        entity_emb, node_b, gfcn_b, wsS, bias_af, out);
  }
}

// Round 12
// 221.857 us; speedup vs baseline: 1.2382x; 1.2382x over previous
//
#include <hip/hip_runtime.h>
#include <hip/hip_bf16.h>

typedef short bf16x8 __attribute__((ext_vector_type(8)));
typedef float f32x4 __attribute__((ext_vector_type(4)));
#define MFMA16 __builtin_amdgcn_mfma_f32_16x16x32_bf16

// ---- split-bf16 helpers -----------------------------------------------------
__device__ __forceinline__ unsigned short rne_bf16(float f) {
  unsigned u = __builtin_bit_cast(unsigned, f);
  return (unsigned short)((u + 0x7fffu + ((u >> 16) & 1u)) >> 16);
}
__device__ __forceinline__ float bf16f(unsigned short h) {
  unsigned u = ((unsigned)h) << 16;
  return __builtin_bit_cast(float, u);
}
__device__ __forceinline__ void split2(float f, short& h, short& l) {
  unsigned short hh = rne_bf16(f);
  h = (short)hh;
  l = (short)rne_bf16(f - bf16f(hh));
}

// ---- ws layout --------------------------------------------------------------
constexpr int NW_SH = 32768;   // node_W  256x128
constexpr int WC_SH = 16384;   // WcEt    128x128
constexpr int GF_SH = 65536;   // gfcn    128x512
constexpr int OFF_NWH = 0;
constexpr int OFF_NWL = NW_SH;
constexpr int OFF_WCH = 2 * NW_SH;
constexpr int OFF_WCL = 2 * NW_SH + WC_SH;
constexpr int OFF_GFH = 2 * NW_SH + 2 * WC_SH;
constexpr int OFF_GFL = 2 * NW_SH + 2 * WC_SH + GF_SH;
constexpr size_t OFF_BIAS_BYTES = (size_t)(2 * NW_SH + 2 * WC_SH + 2 * GF_SH) * 2; // 458752
constexpr size_t OFF_VF_BYTES = OFF_BIAS_BYTES + 6 * 128 * 4;                      // 461824
constexpr int NT_MAX = 2048;                    // B/16
constexpr int VF_SH = NT_MAX * 4 * 4 * 64 * 8;  // 16777216 shorts per plane
constexpr size_t WS_NEED = OFF_VF_BYTES + (size_t)2 * (size_t)VF_SH * 2;           // ~67.6 MB

// ---- setup: pack weights into MFMA fragment layout (hi/lo bf16 planes) ------
__global__ __launch_bounds__(256) void setup_kernel(
    const float* __restrict__ node_W, const float* __restrict__ conv_W,
    const float* __restrict__ gfcn_W, const float* __restrict__ role_emb,
    const float* __restrict__ conv_b, const float* __restrict__ bn_gamma,
    const float* __restrict__ bn_beta, const float* __restrict__ bn_mean,
    const float* __restrict__ bn_var, short* __restrict__ wsS,
    float* __restrict__ bias_af) {
  int idx = blockIdx.x * 256 + threadIdx.x;
  int stride = gridDim.x * 256;
  for (int i = idx; i < 115456; i += stride) {
    if (i < 114688) {
      int j = i & 7, lane = (i >> 3) & 63;
      int kq = ((lane >> 4) & 3) * 8 + j, n16 = lane & 15;
      float val;
      short *ph, *pl;
      int loc;
      if (i < NW_SH) {
        loc = i;
        int f = i >> 9, kf = f & 7, nfr = f >> 3;
        int k = kf * 32 + kq, n = nfr * 16 + n16;
        val = node_W[k * 128 + n];
        ph = wsS + OFF_NWH; pl = wsS + OFF_NWL;
      } else if (i < NW_SH + WC_SH) {
        loc = i - NW_SH;
        int f = loc >> 9, kf = f & 3, nfr = f >> 2;
        int k = kf * 32 + kq, n = nfr * 16 + n16;
        float s = bn_gamma[n] * rsqrtf(bn_var[n] + 1e-5f);
        val = s * conv_W[n * 256 + 128 + k];     // WcEt[e=k][f=n]
        ph = wsS + OFF_WCH; pl = wsS + OFF_WCL;
      } else {
        loc = i - NW_SH - WC_SH;
        int f = loc >> 9, kf = f & 3, nfr = f >> 2;   // nfr 0..31
        int k = kf * 32 + kq, n = nfr * 16 + n16;     // n 0..511
        val = (n < 256) ? gfcn_W[k * 256 + n]
                        : gfcn_W[(128 + k) * 256 + (n - 256)];
        ph = wsS + OFF_GFH; pl = wsS + OFF_GFL;
      }
      short h, l;
      split2(val, h, l);
      ph[loc] = h; pl[loc] = l;
    } else {
      int loc = i - 114688;
      int a = loc >> 7, fc = loc & 127;
      int role = (a == 5) ? 6 : a;   // ROLES = {0,1,2,3,4,6}
      float s = bn_gamma[fc] * rsqrtf(bn_var[fc] + 1e-5f);
      float dot = 0.f;
      for (int e = 0; e < 128; ++e)
        dot = fmaf(role_emb[role * 128 + e], conv_W[fc * 256 + e], dot);
      bias_af[loc] = s * (dot + conv_b[fc] - bn_mean[fc]) + bn_beta[fc];
    }
  }
}

// ---- kernel A: 1 wave/block, global_load_lds staged gather ------------------
// block = (tile, id-column a). LDS: 8KB stage (16 rows x 512B half-row),
// reused as 16x128 hi/lo transpose planes in the epilogue.
// Swizzle: LDS 16B-slot s of row r holds global col16 (s ^ (r&7));
// read of col c looks at slot (c ^ (r&7)) -> 2-way-free bank pattern.
__global__ __launch_bounds__(64) void ent_kernel(
    const int* __restrict__ a_ids, const int* __restrict__ b_ids,
    const int* __restrict__ c_ids, const int* __restrict__ event_ids,
    const float* __restrict__ nf, const float* __restrict__ ent,
    const float* __restrict__ node_b, const short* __restrict__ wsS,
    short* __restrict__ vfh, short* __restrict__ vfl) {
  __shared__ __align__(16) unsigned char stage[8192];
  const int lane = threadIdx.x;
  const int r15 = lane & 15, q = lane >> 4;
  const int bid = blockIdx.x;
  const int tile = bid >> 2, a = bid & 3;
  const int b0 = tile * 16;

  const bf16x8* nwh = (const bf16x8*)(wsS + OFF_NWH);
  const bf16x8* nwl = (const bf16x8*)(wsS + OFF_NWL);

  // id-column a; stack order a,event,b,c
  const int* pw = (a == 0) ? a_ids : (a == 1) ? event_ids
                : (a == 2) ? b_ids : c_ids;
  int idv = pw[b0 + r15];
  int eid[4];
  #pragma unroll
  for (int rg = 0; rg < 4; ++rg) eid[rg] = __shfl(idv, q * 4 + rg);

  // ---- async stage of one K-half: 8 instructions, 2 rows each ---------------
  auto STAGE_HALF = [&](int half) {
    #pragma unroll
    for (int i = 0; i < 8; ++i) {
      int rsel = 2 * i + (lane >> 5);
      int idr = __shfl(idv, rsel);
      int c16 = (lane & 31) ^ (rsel & 7);           // inverse-swizzled source
      const float* gp = nf + (size_t)idr * 256 + half * 128 + c16 * 4;
      __builtin_amdgcn_global_load_lds(
          (const __attribute__((address_space(1))) unsigned int*)(const void*)gp,
          (__attribute__((address_space(3))) unsigned int*)(void*)(stage + i * 1024),
          16, 0, 0);
    }
  };

  // ---- compute one K-half from stage ----------------------------------------
  auto COMP_HALF = [&](int half, f32x4 (&acc)[8]) {
    #pragma unroll
    for (int kk = 0; kk < 4; ++kk) {
      int ks = half * 4 + kk;
      int c = kk * 8 + q * 2;                        // col16 within half
      int s0 = (c ^ (r15 & 7)) * 16;
      int s1 = ((c + 1) ^ (r15 & 7)) * 16;
      float4 f0 = *(const float4*)(stage + r15 * 512 + s0);
      float4 f1 = *(const float4*)(stage + r15 * 512 + s1);
      bf16x8 Fh, Fl;
      #pragma unroll
      for (int j = 0; j < 4; ++j) {
        short h, l;
        split2(f0[j], h, l); Fh[j] = h; Fl[j] = l;
        split2(f1[j], h, l); Fh[4 + j] = h; Fl[4 + j] = l;
      }
      #pragma unroll
      for (int n8 = 0; n8 < 8; ++n8) {
        bf16x8 bh = nwh[(n8 * 8 + ks) * 64 + lane];
        bf16x8 bl = nwl[(n8 * 8 + ks) * 64 + lane];
        acc[n8] = MFMA16(Fh, bh, acc[n8], 0, 0, 0);
        acc[n8] = MFMA16(Fl, bh, acc[n8], 0, 0, 0);
        acc[n8] = MFMA16(Fh, bl, acc[n8], 0, 0, 0);
      }
    }
  };

  // ---- pipeline -------------------------------------------------------------
  STAGE_HALF(0);
  __builtin_amdgcn_sched_barrier(0);
  float ev[32];                                      // issue ev early (32 regs)
  #pragma unroll
  for (int n8 = 0; n8 < 8; ++n8)
    #pragma unroll
    for (int rg = 0; rg < 4; ++rg)
      ev[n8 * 4 + rg] = ent[(size_t)eid[rg] * 128 + n8 * 16 + r15];
  __builtin_amdgcn_sched_barrier(0);
  asm volatile("s_waitcnt vmcnt(32)" ::: "memory");  // H0 stage done, ev in flight
  __builtin_amdgcn_sched_barrier(0);

  f32x4 acc[8];
  #pragma unroll
  for (int n8 = 0; n8 < 8; ++n8) acc[n8] = (f32x4){0.f, 0.f, 0.f, 0.f};
  COMP_HALF(0, acc);

  asm volatile("s_waitcnt lgkmcnt(0)" ::: "memory"); // H0 stage reads drained
  __builtin_amdgcn_sched_barrier(0);
  STAGE_HALF(1);
  __builtin_amdgcn_sched_barrier(0);
  asm volatile("s_waitcnt vmcnt(0)" ::: "memory");   // H1 stage + ev done
  __builtin_amdgcn_sched_barrier(0);
  COMP_HALF(1, acc);

  asm volatile("s_waitcnt lgkmcnt(0)" ::: "memory"); // H1 stage reads drained
  __builtin_amdgcn_sched_barrier(0);

  // ---- epilogue: combine, transpose in stage (now dead), store frags --------
  short* hi = (short*)stage;                         // 16x128 bf16 hi plane
  short* lo = (short*)(stage + 4096);                // lo plane
  #pragma unroll
  for (int n8 = 0; n8 < 8; ++n8) {
    int col = n8 * 16 + r15;
    float nb = node_b[col];
    #pragma unroll
    for (int rg = 0; rg < 4; ++rg) {
      float v = ev[n8 * 4 + rg] + fmaxf(acc[n8][rg] + nb, 0.f);
      short h, l; split2(v, h, l);
      int rr = q * 4 + rg;
      int si = rr * 128 + (col ^ ((rr & 7) << 3));
      hi[si] = h; lo[si] = l;
    }
  }
  asm volatile("s_waitcnt lgkmcnt(0)" ::: "memory");
  __builtin_amdgcn_sched_barrier(0);
  #pragma unroll
  for (int ks = 0; ks < 4; ++ks) {
    int k0 = ks * 32 + q * 8;
    int si = r15 * 128 + (k0 ^ ((r15 & 7) << 3));
    ((bf16x8*)vfh)[((tile * 4 + a) * 4 + ks) * 64 + lane] = *(const bf16x8*)&hi[si];
    ((bf16x8*)vfl)[((tile * 4 + a) * 4 + ks) * 64 + lane] = *(const bf16x8*)&lo[si];
  }
}

// ---- kernel B: stages C+D, 512 threads / 8 waves, merged-jn D ---------------
__global__ __launch_bounds__(512) void head_kernel(
    const float* __restrict__ cond, const float* __restrict__ text,
    const float* __restrict__ gfcn_b, const short* __restrict__ wsS,
    const float* __restrict__ bias_af, const short* __restrict__ vfh,
    const short* __restrict__ vfl, float* __restrict__ out) {
  __shared__ __align__(16) unsigned char smem[49152];
  short* lds_hi = (short*)smem;                 // 96x128 bf16 hi plane
  short* lds_lo = (short*)(smem + 24576);       // lo plane
  float* umin_s = (float*)smem;                 // overlay after planes dead
  constexpr int OV = 260;

  const int t = threadIdx.x;
  const int wv = t >> 6, lane = t & 63;
  const int r15 = lane & 15, q = lane >> 4;
  const int tile = blockIdx.x;
  const int b0 = tile * 16;

  const bf16x8* wch = (const bf16x8*)(wsS + OFF_WCH);
  const bf16x8* wcl = (const bf16x8*)(wsS + OFF_WCL);
  const bf16x8* gfh = (const bf16x8*)(wsS + OFF_GFH);
  const bf16x8* gfl = (const bf16x8*)(wsS + OFF_GFL);
  const bf16x8* vfh8 = (const bf16x8*)vfh;
  const bf16x8* vfl8 = (const bf16x8*)vfl;

  // ---- Phase 0: stage cond/text rows (a=4,5) into plane rows 64..95 ---------
  #pragma unroll
  for (int j = 0; j < 8; ++j) {
    int i = j * 512 + t;
    int arr = i >> 11, rem = i & 2047, r = rem >> 7, e = rem & 127;
    const float* src = arr ? text : cond;
    float v = src[(size_t)(b0 + r) * 128 + e];
    short h, l;
    split2(v, h, l);
    int row = (4 + arr) * 16 + r;
    int si = row * 128 + (e ^ ((row & 7) << 3));
    lds_hi[si] = h; lds_lo[si] = l;
  }
  __syncthreads();

  // ---- Stage C: x = relu(vals @ WcEt + bias_af); wave owns n-frag wv --------
  {
    f32x4 xacc[6];
    #pragma unroll
    for (int a = 0; a < 6; ++a) xacc[a] = (f32x4){0.f, 0.f, 0.f, 0.f};
    #pragma unroll
    for (int ks = 0; ks < 4; ++ks) {
      int k0 = ks * 32 + q * 8;
      bf16x8 bh = wch[(wv * 4 + ks) * 64 + lane];
      bf16x8 bl = wcl[(wv * 4 + ks) * 64 + lane];
      #pragma unroll
      for (int ha = 0; ha < 2; ++ha) {
        bf16x8 ah[3], al[3];
        #pragma unroll
        for (int j = 0; j < 3; ++j) {
          int a = ha * 3 + j;
          if (a < 4) {
            ah[j] = vfh8[((tile * 4 + a) * 4 + ks) * 64 + lane];
            al[j] = vfl8[((tile * 4 + a) * 4 + ks) * 64 + lane];
          } else {
            int row = a * 16 + r15;
            int si = row * 128 + (k0 ^ ((row & 7) << 3));
            ah[j] = *(const bf16x8*)&lds_hi[si];
            al[j] = *(const bf16x8*)&lds_lo[si];
          }
        }
        __builtin_amdgcn_s_setprio(1);
        #pragma unroll
        for (int j = 0; j < 3; ++j) {
          int a = ha * 3 + j;
          xacc[a] = MFMA16(ah[j], bh, xacc[a], 0, 0, 0);
          xacc[a] = MFMA16(al[j], bh, xacc[a], 0, 0, 0);
          xacc[a] = MFMA16(ah[j], bl, xacc[a], 0, 0, 0);
        }
        __builtin_amdgcn_s_setprio(0);
      }
    }
    __syncthreads();   // all cond/text plane reads done before x overwrites
    #pragma unroll
    for (int a = 0; a < 6; ++a) {
      int col = wv * 16 + r15;
      float bv = bias_af[a * 128 + col];
      #pragma unroll
      for (int rg = 0; rg < 4; ++rg) {
        float v = fmaxf(xacc[a][rg] + bv, 0.f);
        short h, l; split2(v, h, l);
        int row = a * 16 + q * 4 + rg;
        int si = row * 128 + (col ^ ((row & 7) << 3));
        lds_hi[si] = h; lds_lo[si] = l;
      }
    }
  }
  __syncthreads();

  // ---- Stage D: u/v = x @ gfcn; acc[6][4] merged, A-frag reused 12x ---------
  f32x4 acc[6][4];
  #pragma unroll
  for (int a = 0; a < 6; ++a)
    #pragma unroll
    for (int jn = 0; jn < 4; ++jn) acc[a][jn] = (f32x4){0.f, 0.f, 0.f, 0.f};
  #pragma unroll
  for (int ks = 0; ks < 4; ++ks) {
    int k0 = ks * 32 + q * 8;
    bf16x8 bh[4], bl[4];
    #pragma unroll
    for (int jn = 0; jn < 4; ++jn) {
      int nfg = wv * 4 + jn;
      bh[jn] = gfh[(nfg * 4 + ks) * 64 + lane];
      bl[jn] = gfl[(nfg * 4 + ks) * 64 + lane];
    }
    #pragma unroll
    for (int ha = 0; ha < 2; ++ha) {
      bf16x8 ah[3], al[3];
      #pragma unroll
      for (int j = 0; j < 3; ++j) {
        int row = (ha * 3 + j) * 16 + r15;
        int si = row * 128 + (k0 ^ ((row & 7) << 3));
        ah[j] = *(const bf16x8*)&lds_hi[si];
        al[j] = *(const bf16x8*)&lds_lo[si];
      }
      __builtin_amdgcn_s_setprio(1);
      #pragma unroll
      for (int jn = 0; jn < 4; ++jn) {
        #pragma unroll
        for (int j = 0; j < 3; ++j) {
          int a = ha * 3 + j;
          acc[a][jn] = MFMA16(ah[j], bh[jn], acc[a][jn], 0, 0, 0);
          acc[a][jn] = MFMA16(al[j], bh[jn], acc[a][jn], 0, 0, 0);
          acc[a][jn] = MFMA16(ah[j], bl[jn], acc[a][jn], 0, 0, 0);
        }
      }
      __builtin_amdgcn_s_setprio(0);
    }
  }
  f32x4 mreg[4];
  #pragma unroll
  for (int jn = 0; jn < 4; ++jn) {
    #pragma unroll
    for (int rg = 0; rg < 4; ++rg) {
      float mm = acc[0][jn][rg];
      #pragma unroll
      for (int a = 1; a < 6; ++a) mm = fminf(mm, acc[a][jn][rg]);
      mreg[jn][rg] = mm;
    }
  }
  __syncthreads();   // all x reads done; planes now dead

  if (wv < 4) {      // u waves: write umin to overlay
    #pragma unroll
    for (int j = 0; j < 4; ++j) {
      int colg = wv * 64 + j * 16 + r15;
      #pragma unroll
      for (int rg = 0; rg < 4; ++rg)
        umin_s[(q * 4 + rg) * OV + colg] = mreg[j][rg];
    }
  }
  __syncthreads();
  if (wv >= 4) {     // v waves: combine in-reg vmin with LDS umin, write out
    #pragma unroll
    for (int j = 0; j < 4; ++j) {
      int g = (wv - 4) * 64 + j * 16 + r15;
      float gbv = gfcn_b[g];
      #pragma unroll
      for (int rg = 0; rg < 4; ++rg) {
        int r = q * 4 + rg;
        out[(size_t)(b0 + r) * 256 + g] =
            fmaxf(umin_s[r * OV + g] + mreg[j][rg] + gbv, 0.f);
      }
    }
  }
}

// ---- fallback: fused (R5 structure, no min-wave bound) ----------------------
__global__ __launch_bounds__(256) void fused_fallback(
    const int* __restrict__ a_ids, const int* __restrict__ b_ids,
    const int* __restrict__ c_ids, const int* __restrict__ event_ids,
    const float* __restrict__ nf, const float* __restrict__ cond,
    const float* __restrict__ text, const float* __restrict__ ent,
    const float* __restrict__ node_b, const float* __restrict__ gfcn_b,
    const short* __restrict__ wsS, const float* __restrict__ bias_af,
    float* __restrict__ out) {
  __shared__ __align__(16) unsigned char smem[49152];
  short* lds_hi = (short*)smem;
  short* lds_lo = (short*)(smem + 24576);
  float* umin_s = (float*)smem;
  float* vmin_s = (float*)(smem + 16640);
  constexpr int OV = 260;

  const int t = threadIdx.x;
  const int wv = t >> 6, lane = t & 63;
  const int r15 = lane & 15, q = lane >> 4;
  const int b0 = blockIdx.x * 16;

  const bf16x8* nwh = (const bf16x8*)(wsS + OFF_NWH);
  const bf16x8* nwl = (const bf16x8*)(wsS + OFF_NWL);
  const bf16x8* wch = (const bf16x8*)(wsS + OFF_WCH);
  const bf16x8* wcl = (const bf16x8*)(wsS + OFF_WCL);
  const bf16x8* gfh = (const bf16x8*)(wsS + OFF_GFH);
  const bf16x8* gfl = (const bf16x8*)(wsS + OFF_GFL);

  const int* pw = (wv == 0) ? a_ids : (wv == 1) ? event_ids
                : (wv == 2) ? b_ids : c_ids;
  int my_id = pw[b0 + r15];
  int eid[4];
  #pragma unroll
  for (int rg = 0; rg < 4; ++rg) eid[rg] = pw[b0 + q * 4 + rg];
  const float* arow = nf + (size_t)my_id * 256 + q * 8;

  float4 avA[8];
  #pragma unroll
  for (int ks = 0; ks < 4; ++ks) {
    avA[2 * ks]     = *(const float4*)(arow + ks * 32);
    avA[2 * ks + 1] = *(const float4*)(arow + ks * 32 + 4);
  }
  #pragma unroll
  for (int j = 0; j < 16; ++j) {
    int i = j * 256 + t;
    int arr = i >> 11, rem = i & 2047, r = rem >> 7, e = rem & 127;
    const float* src = arr ? text : cond;
    float v = src[(size_t)(b0 + r) * 128 + e];
    short h, l;
    split2(v, h, l);
    int row = (4 + arr) * 16 + r;
    int si = row * 128 + (e ^ ((row & 7) << 3));
    lds_hi[si] = h; lds_lo[si] = l;
  }
  {
    f32x4 acc[8];
    #pragma unroll
    for (int n8 = 0; n8 < 8; ++n8) acc[n8] = (f32x4){0.f, 0.f, 0.f, 0.f};
    float4 avB[8];
    #pragma unroll
    for (int ks = 0; ks < 4; ++ks) {
      avB[2 * ks]     = *(const float4*)(arow + (4 + ks) * 32);
      avB[2 * ks + 1] = *(const float4*)(arow + (4 + ks) * 32 + 4);
    }
    #pragma unroll
    for (int ks = 0; ks < 8; ++ks) {
      bf16x8 ah, al;
      {
        float4 v0 = (ks < 4) ? avA[2 * ks] : avB[2 * (ks - 4)];
        float4 v1 = (ks < 4) ? avA[2 * ks + 1] : avB[2 * (ks - 4) + 1];
        #pragma unroll
        for (int j = 0; j < 4; ++j) {
          short h, l;
          split2(v0[j], h, l);
          ah[j] = h; al[j] = l;
          split2(v1[j], h, l);
          ah[4 + j] = h; al[4 + j] = l;
        }
      }
      #pragma unroll
      for (int n8 = 0; n8 < 8; ++n8) {
        bf16x8 bh = nwh[(n8 * 8 + ks) * 64 + lane];
        bf16x8 bl = nwl[(n8 * 8 + ks) * 64 + lane];
        acc[n8] = MFMA16(ah, bh, acc[n8], 0, 0, 0);
        acc[n8] = MFMA16(al, bh, acc[n8], 0, 0, 0);
        acc[n8] = MFMA16(ah, bl, acc[n8], 0, 0, 0);
      }
    }
    float ev[32];
    #pragma unroll
    for (int n8 = 0; n8 < 8; ++n8)
      #pragma unroll
      for (int rg = 0; rg < 4; ++rg)
        ev[n8 * 4 + rg] = ent[(size_t)eid[rg] * 128 + n8 * 16 + r15];
    #pragma unroll
    for (int n8 = 0; n8 < 8; ++n8) {
      int col = n8 * 16 + r15;
      float nb = node_b[col];
      #pragma unroll
      for (int rg = 0; rg < 4; ++rg) {
        float v = ev[n8 * 4 + rg] + fmaxf(acc[n8][rg] + nb, 0.f);
        short h, l; split2(v, h, l);
        int row = wv * 16 + q * 4 + rg;
        int si = row * 128 + (col ^ ((row & 7) << 3));
        lds_hi[si] = h; lds_lo[si] = l;
      }
    }
  }
  __syncthreads();
  {
    f32x4 xacc[6][2];
    #pragma unroll
    for (int a = 0; a < 6; ++a) {
      xacc[a][0] = (f32x4){0.f, 0.f, 0.f, 0.f};
      xacc[a][1] = (f32x4){0.f, 0.f, 0.f, 0.f};
    }
    #pragma unroll
    for (int ks = 0; ks < 4; ++ks) {
      int k0 = ks * 32 + q * 8;
      #pragma unroll
      for (int ha = 0; ha < 2; ++ha) {
        bf16x8 ah[3], al[3];
        #pragma unroll
        for (int j = 0; j < 3; ++j) {
          int row = (ha * 3 + j) * 16 + r15;
          int si = row * 128 + (k0 ^ ((row & 7) << 3));
          ah[j] = *(const bf16x8*)&lds_hi[si];
          al[j] = *(const bf16x8*)&lds_lo[si];
        }
        #pragma unroll
        for (int jn = 0; jn < 2; ++jn) {
          bf16x8 bh = wch[((wv * 2 + jn) * 4 + ks) * 64 + lane];
          bf16x8 bl = wcl[((wv * 2 + jn) * 4 + ks) * 64 + lane];
          #pragma unroll
          for (int j = 0; j < 3; ++j) {
            int a = ha * 3 + j;
            xacc[a][jn] = MFMA16(ah[j], bh, xacc[a][jn], 0, 0, 0);
            xacc[a][jn] = MFMA16(al[j], bh, xacc[a][jn], 0, 0, 0);
            xacc[a][jn] = MFMA16(ah[j], bl, xacc[a][jn], 0, 0, 0);
          }
        }
      }
    }
    __syncthreads();
    #pragma unroll
    for (int a = 0; a < 6; ++a) {
      #pragma unroll
      for (int jn = 0; jn < 2; ++jn) {
        int col = (wv * 2 + jn) * 16 + r15;
        float bv = bias_af[a * 128 + col];
        #pragma unroll
        for (int rg = 0; rg < 4; ++rg) {
          float v = fmaxf(xacc[a][jn][rg] + bv, 0.f);
          short h, l; split2(v, h, l);
          int row = a * 16 + q * 4 + rg;
          int si = row * 128 + (col ^ ((row & 7) << 3));
          lds_hi[si] = h; lds_lo[si] = l;
        }
      }
    }
  }
  __syncthreads();
  f32x4 mreg[8];
  #pragma unroll
  for (int grp = 0; grp < 4; ++grp) {
    f32x4 acc[6][2];
    #pragma unroll
    for (int a = 0; a < 6; ++a) {
      acc[a][0] = (f32x4){0.f, 0.f, 0.f, 0.f};
      acc[a][1] = (f32x4){0.f, 0.f, 0.f, 0.f};
    }
    #pragma unroll
    for (int ks = 0; ks < 4; ++ks) {
      int k0 = ks * 32 + q * 8;
      #pragma unroll
      for (int ha = 0; ha < 2; ++ha) {
        bf16x8 ah[3], al[3];
        #pragma unroll
        for (int j = 0; j < 3; ++j) {
          int row = (ha * 3 + j) * 16 + r15;
          int si = row * 128 + (k0 ^ ((row & 7) << 3));
          ah[j] = *(const bf16x8*)&lds_hi[si];
          al[j] = *(const bf16x8*)&lds_lo[si];
        }
        #pragma unroll
        for (int jn = 0; jn < 2; ++jn) {
          int nfg = wv * 8 + grp * 2 + jn;
          bf16x8 bh = gfh[(nfg * 4 + ks) * 64 + lane];
          bf16x8 bl = gfl[(nfg * 4 + ks) * 64 + lane];
          #pragma unroll
          for (int j = 0; j < 3; ++j) {
            int a = ha * 3 + j;
            acc[a][jn] = MFMA16(ah[j], bh, acc[a][jn], 0, 0, 0);
            acc[a][jn] = MFMA16(al[j], bh, acc[a][jn], 0, 0, 0);
            acc[a][jn] = MFMA16(ah[j], bl, acc[a][jn], 0, 0, 0);
          }
        }
      }
    }
    #pragma unroll
    for (int jn = 0; jn < 2; ++jn) {
      #pragma unroll
      for (int rg = 0; rg < 4; ++rg) {
        float mm = acc[0][jn][rg];
        #pragma unroll
        for (int a = 1; a < 6; ++a) mm = fminf(mm, acc[a][jn][rg]);
        mreg[grp * 2 + jn][rg] = mm;
      }
    }
  }
  __syncthreads();
  {
    float* dst = (wv >= 2) ? vmin_s : umin_s;
    int cbase = (wv & 1) * 128;
    #pragma unroll
    for (int j = 0; j < 8; ++j) {
      int colg = cbase + j * 16 + r15;
      #pragma unroll
      for (int rg = 0; rg < 4; ++rg)
        dst[(q * 4 + rg) * OV + colg] = mreg[j][rg];
    }
  }
  __syncthreads();
  #pragma unroll
  for (int j = 0; j < 16; ++j) {
    int i = j * 256 + t;
    int r = i >> 8, g = i & 255;
    out[(size_t)(b0 + r) * 256 + g] =
        fmaxf(umin_s[r * OV + g] + vmin_s[r * OV + g] + gfcn_b[g], 0.f);
  }
}

extern "C" void kernel_launch(void* const* d_in, const int* in_sizes, int n_in,
                              void* d_out, int out_size, void* d_ws, size_t ws_size,
                              hipStream_t stream) {
  const int* a_ids = (const int*)d_in[0];
  const int* b_ids = (const int*)d_in[1];
  const int* c_ids = (const int*)d_in[2];
  const int* event_ids = (const int*)d_in[3];
  const float* node_features = (const float*)d_in[4];
  const float* cond_rel = (const float*)d_in[5];
  const float* text = (const float*)d_in[6];
  const float* entity_emb = (const float*)d_in[7];
  const float* role_emb = (const float*)d_in[8];
  const float* node_W = (const float*)d_in[9];
  const float* node_b = (const float*)d_in[10];
  const float* conv_W = (const float*)d_in[11];
  const float* conv_b = (const float*)d_in[12];
  const float* bn_gamma = (const float*)d_in[13];
  const float* bn_beta = (const float*)d_in[14];
  const float* bn_mean = (const float*)d_in[15];
  const float* bn_var = (const float*)d_in[16];
  const float* gfcn_W = (const float*)d_in[17];
  const float* gfcn_b = (const float*)d_in[18];
  float* out = (float*)d_out;

  short* wsS = (short*)d_ws;
  float* bias_af = (float*)((char*)d_ws + OFF_BIAS_BYTES);
  const int B = in_sizes[0];   // 32768
  const int NT = B / 16;       // 2048

  setup_kernel<<<452, 256, 0, stream>>>(node_W, conv_W, gfcn_W, role_emb,
                                        conv_b, bn_gamma, bn_beta, bn_mean,
                                        bn_var, wsS, bias_af);
  if (ws_size >= WS_NEED && NT <= NT_MAX) {
    short* vfh = (short*)((char*)d_ws + OFF_VF_BYTES);
    short* vfl = vfh + VF_SH;
    ent_kernel<<<NT * 4, 64, 0, stream>>>(a_ids, b_ids, c_ids, event_ids,
                                          node_features, entity_emb, node_b,
                                          wsS, vfh, vfl);
    head_kernel<<<NT, 512, 0, stream>>>(cond_rel, text, gfcn_b, wsS, bias_af,
                                        vfh, vfl, out);
  } else {
    fused_fallback<<<NT, 256, 0, stream>>>(
        a_ids, b_ids, c_ids, event_ids, node_features, cond_rel, text,
        entity_emb, node_b, gfcn_b, wsS, bias_af, out);
  }
}

// Round 13
// 191.307 us; speedup vs baseline: 1.4359x; 1.1597x over previous
//
#include <hip/hip_runtime.h>
#include <hip/hip_bf16.h>

typedef short bf16x8 __attribute__((ext_vector_type(8)));
typedef float f32x4 __attribute__((ext_vector_type(4)));
#define MFMA16 __builtin_amdgcn_mfma_f32_16x16x32_bf16

// ---- split-bf16 helpers -----------------------------------------------------
__device__ __forceinline__ unsigned short rne_bf16(float f) {
  unsigned u = __builtin_bit_cast(unsigned, f);
  return (unsigned short)((u + 0x7fffu + ((u >> 16) & 1u)) >> 16);
}
__device__ __forceinline__ float bf16f(unsigned short h) {
  unsigned u = ((unsigned)h) << 16;
  return __builtin_bit_cast(float, u);
}
__device__ __forceinline__ void split2(float f, short& h, short& l) {
  unsigned short hh = rne_bf16(f);
  h = (short)hh;
  l = (short)rne_bf16(f - bf16f(hh));
}

// ---- ws layout (weights + bias only; vf eliminated) -------------------------
constexpr int NW_SH = 32768;   // node_W  256x128
constexpr int WC_SH = 16384;   // WcEt    128x128
constexpr int GF_SH = 65536;   // gfcn    128x512
constexpr int OFF_NWH = 0;
constexpr int OFF_NWL = NW_SH;
constexpr int OFF_WCH = 2 * NW_SH;
constexpr int OFF_WCL = 2 * NW_SH + WC_SH;
constexpr int OFF_GFH = 2 * NW_SH + 2 * WC_SH;
constexpr int OFF_GFL = 2 * NW_SH + 2 * WC_SH + GF_SH;
constexpr size_t OFF_BIAS_BYTES = (size_t)(2 * NW_SH + 2 * WC_SH + 2 * GF_SH) * 2; // 458752
constexpr size_t WS_NEED = OFF_BIAS_BYTES + 6 * 128 * 4;                            // ~462 KB

// ---- setup: pack weights into MFMA fragment layout (hi/lo bf16 planes) ------
__global__ __launch_bounds__(256) void setup_kernel(
    const float* __restrict__ node_W, const float* __restrict__ conv_W,
    const float* __restrict__ gfcn_W, const float* __restrict__ role_emb,
    const float* __restrict__ conv_b, const float* __restrict__ bn_gamma,
    const float* __restrict__ bn_beta, const float* __restrict__ bn_mean,
    const float* __restrict__ bn_var, short* __restrict__ wsS,
    float* __restrict__ bias_af) {
  int idx = blockIdx.x * 256 + threadIdx.x;
  int stride = gridDim.x * 256;
  for (int i = idx; i < 115456; i += stride) {
    if (i < 114688) {
      int j = i & 7, lane = (i >> 3) & 63;
      int kq = ((lane >> 4) & 3) * 8 + j, n16 = lane & 15;
      float val;
      short *ph, *pl;
      int loc;
      if (i < NW_SH) {
        loc = i;
        int f = i >> 9, kf = f & 7, nfr = f >> 3;
        int k = kf * 32 + kq, n = nfr * 16 + n16;
        val = node_W[k * 128 + n];
        ph = wsS + OFF_NWH; pl = wsS + OFF_NWL;
      } else if (i < NW_SH + WC_SH) {
        loc = i - NW_SH;
        int f = loc >> 9, kf = f & 3, nfr = f >> 2;
        int k = kf * 32 + kq, n = nfr * 16 + n16;
        float s = bn_gamma[n] * rsqrtf(bn_var[n] + 1e-5f);
        val = s * conv_W[n * 256 + 128 + k];     // WcEt[e=k][f=n]
        ph = wsS + OFF_WCH; pl = wsS + OFF_WCL;
      } else {
        loc = i - NW_SH - WC_SH;
        int f = loc >> 9, kf = f & 3, nfr = f >> 2;   // nfr 0..31
        int k = kf * 32 + kq, n = nfr * 16 + n16;     // n 0..511
        val = (n < 256) ? gfcn_W[k * 256 + n]
                        : gfcn_W[(128 + k) * 256 + (n - 256)];
        ph = wsS + OFF_GFH; pl = wsS + OFF_GFL;
      }
      short h, l;
      split2(val, h, l);
      ph[loc] = h; pl[loc] = l;
    } else {
      int loc = i - 114688;
      int a = loc >> 7, fc = loc & 127;
      int role = (a == 5) ? 6 : a;   // ROLES = {0,1,2,3,4,6}
      float s = bn_gamma[fc] * rsqrtf(bn_var[fc] + 1e-5f);
      float dot = 0.f;
      for (int e = 0; e < 128; ++e)
        dot = fmaf(role_emb[role * 128 + e], conv_W[fc * 256 + e], dot);
      bias_af[loc] = s * (dot + conv_b[fc] - bn_mean[fc]) + bn_beta[fc];
    }
  }
}

// ---- fused2: Stage B + C + D in one kernel, 512 threads / 8 waves -----------
// B: wave wv = (a = wv>>1, half h = wv&1). Stage own K-half of a's nf rows via
// global_load_lds; cond/text staging overlaps gather latency; 96-MFMA quarter
// GEMM per wave; vals written straight into the C-input LDS planes.
__global__ __launch_bounds__(512) void fused2_kernel(
    const int* __restrict__ a_ids, const int* __restrict__ b_ids,
    const int* __restrict__ c_ids, const int* __restrict__ event_ids,
    const float* __restrict__ nf, const float* __restrict__ ent,
    const float* __restrict__ node_b, const float* __restrict__ cond,
    const float* __restrict__ text, const float* __restrict__ gfcn_b,
    const short* __restrict__ wsS, const float* __restrict__ bias_af,
    float* __restrict__ out) {
  __shared__ __align__(16) unsigned char smem[114688];
  short* lds_hi = (short*)smem;                 // 96x128 bf16 hi plane
  short* lds_lo = (short*)(smem + 24576);       // lo plane
  unsigned char* stage = smem + 49152;          // 4 x 16KB nf stage
  float* umin_s = (float*)smem;                 // overlay after planes dead
  constexpr int OV = 260;

  const int t = threadIdx.x;
  const int wv = t >> 6, lane = t & 63;
  const int r15 = lane & 15, q = lane >> 4;
  const int tile = blockIdx.x;
  const int b0 = tile * 16;

  const bf16x8* nwh = (const bf16x8*)(wsS + OFF_NWH);
  const bf16x8* nwl = (const bf16x8*)(wsS + OFF_NWL);
  const bf16x8* wch = (const bf16x8*)(wsS + OFF_WCH);
  const bf16x8* wcl = (const bf16x8*)(wsS + OFF_WCL);
  const bf16x8* gfh = (const bf16x8*)(wsS + OFF_GFH);
  const bf16x8* gfl = (const bf16x8*)(wsS + OFF_GFL);

  // ---- Phase B-stage: wave (aB,hB) stages its K-half of a's 16 nf rows ------
  const int aB = wv >> 1, hB = wv & 1;
  const int* pw = (aB == 0) ? a_ids : (aB == 1) ? event_ids
                : (aB == 2) ? b_ids : c_ids;    // stack order a,event,b,c
  int idv = pw[b0 + r15];
  {
    unsigned char* stg = stage + aB * 16384 + hB * 8192;
    #pragma unroll
    for (int i = 0; i < 8; ++i) {
      int rsel = 2 * i + (lane >> 5);
      int idr = __shfl(idv, rsel);
      int c16 = (lane & 31) ^ (rsel & 7);       // inverse-swizzled source
      const float* gp = nf + (size_t)idr * 256 + hB * 128 + c16 * 4;
      __builtin_amdgcn_global_load_lds(
          (const __attribute__((address_space(1))) unsigned int*)(const void*)gp,
          (__attribute__((address_space(3))) unsigned int*)(void*)(stg + i * 1024),
          16, 0, 0);
    }
  }
  __builtin_amdgcn_sched_barrier(0);

  // ---- cond/text rows (a=4,5) -> plane rows 64..95 (overlaps stage latency) -
  #pragma unroll
  for (int j = 0; j < 8; ++j) {
    int i = j * 512 + t;
    int arr = i >> 11, rem = i & 2047, r = rem >> 7, e = rem & 127;
    const float* src = arr ? text : cond;
    float v = src[(size_t)(b0 + r) * 128 + e];
    short h, l;
    split2(v, h, l);
    int row = (4 + arr) * 16 + r;
    int si = row * 128 + (e ^ ((row & 7) << 3));
    lds_hi[si] = h; lds_lo[si] = l;
  }
  asm volatile("s_waitcnt vmcnt(0)" ::: "memory");   // own stage writes landed
  __builtin_amdgcn_sched_barrier(0);
  __syncthreads();                                    // all stages visible

  // ---- Phase B-compute: quarter-GEMM, acc over n8 in [hB*4, hB*4+4) ---------
  {
    int eid[4];
    #pragma unroll
    for (int rg = 0; rg < 4; ++rg) eid[rg] = pw[b0 + q * 4 + rg];
    float ev[16];
    #pragma unroll
    for (int j4 = 0; j4 < 4; ++j4) {
      int n8 = hB * 4 + j4;
      #pragma unroll
      for (int rg = 0; rg < 4; ++rg)
        ev[j4 * 4 + rg] = ent[(size_t)eid[rg] * 128 + n8 * 16 + r15];
    }
    __builtin_amdgcn_sched_barrier(0);

    f32x4 acc[4];
    #pragma unroll
    for (int j4 = 0; j4 < 4; ++j4) acc[j4] = (f32x4){0.f, 0.f, 0.f, 0.f};
    #pragma unroll
    for (int ks = 0; ks < 8; ++ks) {
      int hh = ks >> 2, kk = ks & 3;
      int c = kk * 8 + q * 2;
      const unsigned char* sb = stage + aB * 16384 + hh * 8192 + r15 * 512;
      float4 f0 = *(const float4*)(sb + ((c ^ (r15 & 7)) * 16));
      float4 f1 = *(const float4*)(sb + (((c + 1) ^ (r15 & 7)) * 16));
      bf16x8 Fh, Fl;
      #pragma unroll
      for (int j = 0; j < 4; ++j) {
        short h, l;
        split2(f0[j], h, l); Fh[j] = h; Fl[j] = l;
        split2(f1[j], h, l); Fh[4 + j] = h; Fl[4 + j] = l;
      }
      #pragma unroll
      for (int j4 = 0; j4 < 4; ++j4) {
        int n8 = hB * 4 + j4;
        bf16x8 bh = nwh[(n8 * 8 + ks) * 64 + lane];
        bf16x8 bl = nwl[(n8 * 8 + ks) * 64 + lane];
        acc[j4] = MFMA16(Fh, bh, acc[j4], 0, 0, 0);
        acc[j4] = MFMA16(Fl, bh, acc[j4], 0, 0, 0);
        acc[j4] = MFMA16(Fh, bl, acc[j4], 0, 0, 0);
      }
    }
    // epilogue: combine with ev, transposed write into plane rows aB*16..+16
    #pragma unroll
    for (int j4 = 0; j4 < 4; ++j4) {
      int n8 = hB * 4 + j4;
      int col = n8 * 16 + r15;
      float nb = node_b[col];
      #pragma unroll
      for (int rg = 0; rg < 4; ++rg) {
        float v = ev[j4 * 4 + rg] + fmaxf(acc[j4][rg] + nb, 0.f);
        short h, l; split2(v, h, l);
        int row = aB * 16 + q * 4 + rg;
        int si = row * 128 + (col ^ ((row & 7) << 3));
        lds_hi[si] = h; lds_lo[si] = l;
      }
    }
  }
  __syncthreads();   // vals (rows 0..63) + cond/text (64..95) all in planes

  // ---- Stage C: x = relu(vals @ WcEt + bias_af); wave owns n-frag wv --------
  {
    f32x4 xacc[6];
    #pragma unroll
    for (int a = 0; a < 6; ++a) xacc[a] = (f32x4){0.f, 0.f, 0.f, 0.f};
    #pragma unroll
    for (int ks = 0; ks < 4; ++ks) {
      int k0 = ks * 32 + q * 8;
      bf16x8 bh = wch[(wv * 4 + ks) * 64 + lane];
      bf16x8 bl = wcl[(wv * 4 + ks) * 64 + lane];
      #pragma unroll
      for (int ha = 0; ha < 2; ++ha) {
        bf16x8 ah[3], al[3];
        #pragma unroll
        for (int j = 0; j < 3; ++j) {
          int a = ha * 3 + j;
          int row = a * 16 + r15;
          int si = row * 128 + (k0 ^ ((row & 7) << 3));
          ah[j] = *(const bf16x8*)&lds_hi[si];
          al[j] = *(const bf16x8*)&lds_lo[si];
        }
        __builtin_amdgcn_s_setprio(1);
        #pragma unroll
        for (int j = 0; j < 3; ++j) {
          int a = ha * 3 + j;
          xacc[a] = MFMA16(ah[j], bh, xacc[a], 0, 0, 0);
          xacc[a] = MFMA16(al[j], bh, xacc[a], 0, 0, 0);
          xacc[a] = MFMA16(ah[j], bl, xacc[a], 0, 0, 0);
        }
        __builtin_amdgcn_s_setprio(0);
      }
    }
    __syncthreads();   // all vals/cond/text reads done before x overwrites
    #pragma unroll
    for (int a = 0; a < 6; ++a) {
      int col = wv * 16 + r15;
      float bv = bias_af[a * 128 + col];
      #pragma unroll
      for (int rg = 0; rg < 4; ++rg) {
        float v = fmaxf(xacc[a][rg] + bv, 0.f);
        short h, l; split2(v, h, l);
        int row = a * 16 + q * 4 + rg;
        int si = row * 128 + (col ^ ((row & 7) << 3));
        lds_hi[si] = h; lds_lo[si] = l;
      }
    }
  }
  __syncthreads();

  // ---- Stage D: u/v = x @ gfcn; acc[6][4] merged, A-frag reused 12x ---------
  f32x4 acc[6][4];
  #pragma unroll
  for (int a = 0; a < 6; ++a)
    #pragma unroll
    for (int jn = 0; jn < 4; ++jn) acc[a][jn] = (f32x4){0.f, 0.f, 0.f, 0.f};
  #pragma unroll
  for (int ks = 0; ks < 4; ++ks) {
    int k0 = ks * 32 + q * 8;
    bf16x8 bh[4], bl[4];
    #pragma unroll
    for (int jn = 0; jn < 4; ++jn) {
      int nfg = wv * 4 + jn;
      bh[jn] = gfh[(nfg * 4 + ks) * 64 + lane];
      bl[jn] = gfl[(nfg * 4 + ks) * 64 + lane];
    }
    #pragma unroll
    for (int ha = 0; ha < 2; ++ha) {
      bf16x8 ah[3], al[3];
      #pragma unroll
      for (int j = 0; j < 3; ++j) {
        int row = (ha * 3 + j) * 16 + r15;
        int si = row * 128 + (k0 ^ ((row & 7) << 3));
        ah[j] = *(const bf16x8*)&lds_hi[si];
        al[j] = *(const bf16x8*)&lds_lo[si];
      }
      __builtin_amdgcn_s_setprio(1);
      #pragma unroll
      for (int jn = 0; jn < 4; ++jn) {
        #pragma unroll
        for (int j = 0; j < 3; ++j) {
          int a = ha * 3 + j;
          acc[a][jn] = MFMA16(ah[j], bh[jn], acc[a][jn], 0, 0, 0);
          acc[a][jn] = MFMA16(al[j], bh[jn], acc[a][jn], 0, 0, 0);
          acc[a][jn] = MFMA16(ah[j], bl[jn], acc[a][jn], 0, 0, 0);
        }
      }
      __builtin_amdgcn_s_setprio(0);
    }
  }
  f32x4 mreg[4];
  #pragma unroll
  for (int jn = 0; jn < 4; ++jn) {
    #pragma unroll
    for (int rg = 0; rg < 4; ++rg) {
      float mm = acc[0][jn][rg];
      #pragma unroll
      for (int a = 1; a < 6; ++a) mm = fminf(mm, acc[a][jn][rg]);
      mreg[jn][rg] = mm;
    }
  }
  __syncthreads();   // all x reads done; planes now dead

  if (wv < 4) {      // u waves: write umin to overlay
    #pragma unroll
    for (int j = 0; j < 4; ++j) {
      int colg = wv * 64 + j * 16 + r15;
      #pragma unroll
      for (int rg = 0; rg < 4; ++rg)
        umin_s[(q * 4 + rg) * OV + colg] = mreg[j][rg];
    }
  }
  __syncthreads();
  if (wv >= 4) {     // v waves: combine in-reg vmin with LDS umin, write out
    #pragma unroll
    for (int j = 0; j < 4; ++j) {
      int g = (wv - 4) * 64 + j * 16 + r15;
      float gbv = gfcn_b[g];
      #pragma unroll
      for (int rg = 0; rg < 4; ++rg) {
        int r = q * 4 + rg;
        out[(size_t)(b0 + r) * 256 + g] =
            fmaxf(umin_s[r * OV + g] + mreg[j][rg] + gbv, 0.f);
      }
    }
  }
}

// ---- fallback: fused (R5 structure, no min-wave bound) ----------------------
__global__ __launch_bounds__(256) void fused_fallback(
    const int* __restrict__ a_ids, const int* __restrict__ b_ids,
    const int* __restrict__ c_ids, const int* __restrict__ event_ids,
    const float* __restrict__ nf, const float* __restrict__ cond,
    const float* __restrict__ text, const float* __restrict__ ent,
    const float* __restrict__ node_b, const float* __restrict__ gfcn_b,
    const short* __restrict__ wsS, const float* __restrict__ bias_af,
    float* __restrict__ out) {
  __shared__ __align__(16) unsigned char smem[49152];
  short* lds_hi = (short*)smem;
  short* lds_lo = (short*)(smem + 24576);
  float* umin_s = (float*)smem;
  float* vmin_s = (float*)(smem + 16640);
  constexpr int OV = 260;

  const int t = threadIdx.x;
  const int wv = t >> 6, lane = t & 63;
  const int r15 = lane & 15, q = lane >> 4;
  const int b0 = blockIdx.x * 16;

  const bf16x8* nwh = (const bf16x8*)(wsS + OFF_NWH);
  const bf16x8* nwl = (const bf16x8*)(wsS + OFF_NWL);
  const bf16x8* wch = (const bf16x8*)(wsS + OFF_WCH);
  const bf16x8* wcl = (const bf16x8*)(wsS + OFF_WCL);
  const bf16x8* gfh = (const bf16x8*)(wsS + OFF_GFH);
  const bf16x8* gfl = (const bf16x8*)(wsS + OFF_GFL);

  const int* pw = (wv == 0) ? a_ids : (wv == 1) ? event_ids
                : (wv == 2) ? b_ids : c_ids;
  int my_id = pw[b0 + r15];
  int eid[4];
  #pragma unroll
  for (int rg = 0; rg < 4; ++rg) eid[rg] = pw[b0 + q * 4 + rg];
  const float* arow = nf + (size_t)my_id * 256 + q * 8;

  float4 avA[8];
  #pragma unroll
  for (int ks = 0; ks < 4; ++ks) {
    avA[2 * ks]     = *(const float4*)(arow + ks * 32);
    avA[2 * ks + 1] = *(const float4*)(arow + ks * 32 + 4);
  }
  #pragma unroll
  for (int j = 0; j < 16; ++j) {
    int i = j * 256 + t;
    int arr = i >> 11, rem = i & 2047, r = rem >> 7, e = rem & 127;
    const float* src = arr ? text : cond;
    float v = src[(size_t)(b0 + r) * 128 + e];
    short h, l;
    split2(v, h, l);
    int row = (4 + arr) * 16 + r;
    int si = row * 128 + (e ^ ((row & 7) << 3));
    lds_hi[si] = h; lds_lo[si] = l;
  }
  {
    f32x4 acc[8];
    #pragma unroll
    for (int n8 = 0; n8 < 8; ++n8) acc[n8] = (f32x4){0.f, 0.f, 0.f, 0.f};
    float4 avB[8];
    #pragma unroll
    for (int ks = 0; ks < 4; ++ks) {
      avB[2 * ks]     = *(const float4*)(arow + (4 + ks) * 32);
      avB[2 * ks + 1] = *(const float4*)(arow + (4 + ks) * 32 + 4);
    }
    #pragma unroll
    for (int ks = 0; ks < 8; ++ks) {
      bf16x8 ah, al;
      {
        float4 v0 = (ks < 4) ? avA[2 * ks] : avB[2 * (ks - 4)];
        float4 v1 = (ks < 4) ? avA[2 * ks + 1] : avB[2 * (ks - 4) + 1];
        #pragma unroll
        for (int j = 0; j < 4; ++j) {
          short h, l;
          split2(v0[j], h, l);
          ah[j] = h; al[j] = l;
          split2(v1[j], h, l);
          ah[4 + j] = h; al[4 + j] = l;
        }
      }
      #pragma unroll
      for (int n8 = 0; n8 < 8; ++n8) {
        bf16x8 bh = nwh[(n8 * 8 + ks) * 64 + lane];
        bf16x8 bl = nwl[(n8 * 8 + ks) * 64 + lane];
        acc[n8] = MFMA16(ah, bh, acc[n8], 0, 0, 0);
        acc[n8] = MFMA16(al, bh, acc[n8], 0, 0, 0);
        acc[n8] = MFMA16(ah, bl, acc[n8], 0, 0, 0);
      }
    }
    float ev[32];
    #pragma unroll
    for (int n8 = 0; n8 < 8; ++n8)
      #pragma unroll
      for (int rg = 0; rg < 4; ++rg)
        ev[n8 * 4 + rg] = ent[(size_t)eid[rg] * 128 + n8 * 16 + r15];
    #pragma unroll
    for (int n8 = 0; n8 < 8; ++n8) {
      int col = n8 * 16 + r15;
      float nb = node_b[col];
      #pragma unroll
      for (int rg = 0; rg < 4; ++rg) {
        float v = ev[n8 * 4 + rg] + fmaxf(acc[n8][rg] + nb, 0.f);
        short h, l; split2(v, h, l);
        int row = wv * 16 + q * 4 + rg;
        int si = row * 128 + (col ^ ((row & 7) << 3));
        lds_hi[si] = h; lds_lo[si] = l;
      }
    }
  }
  __syncthreads();
  {
    f32x4 xacc[6][2];
    #pragma unroll
    for (int a = 0; a < 6; ++a) {
      xacc[a][0] = (f32x4){0.f, 0.f, 0.f, 0.f};
      xacc[a][1] = (f32x4){0.f, 0.f, 0.f, 0.f};
    }
    #pragma unroll
    for (int ks = 0; ks < 4; ++ks) {
      int k0 = ks * 32 + q * 8;
      #pragma unroll
      for (int ha = 0; ha < 2; ++ha) {
        bf16x8 ah[3], al[3];
        #pragma unroll
        for (int j = 0; j < 3; ++j) {
          int row = (ha * 3 + j) * 16 + r15;
          int si = row * 128 + (k0 ^ ((row & 7) << 3));
          ah[j] = *(const bf16x8*)&lds_hi[si];
          al[j] = *(const bf16x8*)&lds_lo[si];
        }
        #pragma unroll
        for (int jn = 0; jn < 2; ++jn) {
          bf16x8 bh = wch[((wv * 2 + jn) * 4 + ks) * 64 + lane];
          bf16x8 bl = wcl[((wv * 2 + jn) * 4 + ks) * 64 + lane];
          #pragma unroll
          for (int j = 0; j < 3; ++j) {
            int a = ha * 3 + j;
            xacc[a][jn] = MFMA16(ah[j], bh, xacc[a][jn], 0, 0, 0);
            xacc[a][jn] = MFMA16(al[j], bh, xacc[a][jn], 0, 0, 0);
            xacc[a][jn] = MFMA16(ah[j], bl, xacc[a][jn], 0, 0, 0);
          }
        }
      }
    }
    __syncthreads();
    #pragma unroll
    for (int a = 0; a < 6; ++a) {
      #pragma unroll
      for (int jn = 0; jn < 2; ++jn) {
        int col = (wv * 2 + jn) * 16 + r15;
        float bv = bias_af[a * 128 + col];
        #pragma unroll
        for (int rg = 0; rg < 4; ++rg) {
          float v = fmaxf(xacc[a][jn][rg] + bv, 0.f);
          short h, l; split2(v, h, l);
          int row = a * 16 + q * 4 + rg;
          int si = row * 128 + (col ^ ((row & 7) << 3));
          lds_hi[si] = h; lds_lo[si] = l;
        }
      }
    }
  }
  __syncthreads();
  f32x4 mreg[8];
  #pragma unroll
  for (int grp = 0; grp < 4; ++grp) {
    f32x4 acc[6][2];
    #pragma unroll
    for (int a = 0; a < 6; ++a) {
      acc[a][0] = (f32x4){0.f, 0.f, 0.f, 0.f};
      acc[a][1] = (f32x4){0.f, 0.f, 0.f, 0.f};
    }
    #pragma unroll
    for (int ks = 0; ks < 4; ++ks) {
      int k0 = ks * 32 + q * 8;
      #pragma unroll
      for (int ha = 0; ha < 2; ++ha) {
        bf16x8 ah[3], al[3];
        #pragma unroll
        for (int j = 0; j < 3; ++j) {
          int row = (ha * 3 + j) * 16 + r15;
          int si = row * 128 + (k0 ^ ((row & 7) << 3));
          ah[j] = *(const bf16x8*)&lds_hi[si];
          al[j] = *(const bf16x8*)&lds_lo[si];
        }
        #pragma unroll
        for (int jn = 0; jn < 2; ++jn) {
          int nfg = wv * 8 + grp * 2 + jn;
          bf16x8 bh = gfh[(nfg * 4 + ks) * 64 + lane];
          bf16x8 bl = gfl[(nfg * 4 + ks) * 64 + lane];
          #pragma unroll
          for (int j = 0; j < 3; ++j) {
            int a = ha * 3 + j;
            acc[a][jn] = MFMA16(ah[j], bh, acc[a][jn], 0, 0, 0);
            acc[a][jn] = MFMA16(al[j], bh, acc[a][jn], 0, 0, 0);
            acc[a][jn] = MFMA16(ah[j], bl, acc[a][jn], 0, 0, 0);
          }
        }
      }
    }
    #pragma unroll
    for (int jn = 0; jn < 2; ++jn) {
      #pragma unroll
      for (int rg = 0; rg < 4; ++rg) {
        float mm = acc[0][jn][rg];
        #pragma unroll
        for (int a = 1; a < 6; ++a) mm = fminf(mm, acc[a][jn][rg]);
        mreg[grp * 2 + jn][rg] = mm;
      }
    }
  }
  __syncthreads();
  {
    float* dst = (wv >= 2) ? vmin_s : umin_s;
    int cbase = (wv & 1) * 128;
    #pragma unroll
    for (int j = 0; j < 8; ++j) {
      int colg = cbase + j * 16 + r15;
      #pragma unroll
      for (int rg = 0; rg < 4; ++rg)
        dst[(q * 4 + rg) * OV + colg] = mreg[j][rg];
    }
  }
  __syncthreads();
  #pragma unroll
  for (int j = 0; j < 16; ++j) {
    int i = j * 256 + t;
    int r = i >> 8, g = i & 255;
    out[(size_t)(b0 + r) * 256 + g] =
        fmaxf(umin_s[r * OV + g] + vmin_s[r * OV + g] + gfcn_b[g], 0.f);
  }
}

extern "C" void kernel_launch(void* const* d_in, const int* in_sizes, int n_in,
                              void* d_out, int out_size, void* d_ws, size_t ws_size,
                              hipStream_t stream) {
  const int* a_ids = (const int*)d_in[0];
  const int* b_ids = (const int*)d_in[1];
  const int* c_ids = (const int*)d_in[2];
  const int* event_ids = (const int*)d_in[3];
  const float* node_features = (const float*)d_in[4];
  const float* cond_rel = (const float*)d_in[5];
  const float* text = (const float*)d_in[6];
  const float* entity_emb = (const float*)d_in[7];
  const float* role_emb = (const float*)d_in[8];
  const float* node_W = (const float*)d_in[9];
  const float* node_b = (const float*)d_in[10];
  const float* conv_W = (const float*)d_in[11];
  const float* conv_b = (const float*)d_in[12];
  const float* bn_gamma = (const float*)d_in[13];
  const float* bn_beta = (const float*)d_in[14];
  const float* bn_mean = (const float*)d_in[15];
  const float* bn_var = (const float*)d_in[16];
  const float* gfcn_W = (const float*)d_in[17];
  const float* gfcn_b = (const float*)d_in[18];
  float* out = (float*)d_out;

  short* wsS = (short*)d_ws;
  float* bias_af = (float*)((char*)d_ws + OFF_BIAS_BYTES);
  const int B = in_sizes[0];   // 32768
  const int NT = B / 16;       // 2048

  setup_kernel<<<452, 256, 0, stream>>>(node_W, conv_W, gfcn_W, role_emb,
                                        conv_b, bn_gamma, bn_beta, bn_mean,
                                        bn_var, wsS, bias_af);
  if (ws_size >= WS_NEED) {
    fused2_kernel<<<NT, 512, 0, stream>>>(
        a_ids, b_ids, c_ids, event_ids, node_features, entity_emb, node_b,
        cond_rel, text, gfcn_b, wsS, bias_af, out);
  } else {
    fused_fallback<<<NT, 256, 0, stream>>>(
        a_ids, b_ids, c_ids, event_ids, node_features, cond_rel, text,
        entity_emb, node_b, gfcn_b, wsS, bias_af, out);
  }
}

// Round 14
// 173.995 us; speedup vs baseline: 1.5788x; 1.0995x over previous
//
#include <hip/hip_runtime.h>
#include <hip/hip_bf16.h>

typedef short bf16x8 __attribute__((ext_vector_type(8)));
typedef float f32x4 __attribute__((ext_vector_type(4)));
#define MFMA16 __builtin_amdgcn_mfma_f32_16x16x32_bf16

// ---- split-bf16 helpers -----------------------------------------------------
__device__ __forceinline__ unsigned short rne_bf16(float f) {
  unsigned u = __builtin_bit_cast(unsigned, f);
  return (unsigned short)((u + 0x7fffu + ((u >> 16) & 1u)) >> 16);
}
__device__ __forceinline__ float bf16f(unsigned short h) {
  unsigned u = ((unsigned)h) << 16;
  return __builtin_bit_cast(float, u);
}
__device__ __forceinline__ void split2(float f, short& h, short& l) {
  unsigned short hh = rne_bf16(f);
  h = (short)hh;
  l = (short)rne_bf16(f - bf16f(hh));
}

// ---- ws layout (weights + bias only) ----------------------------------------
constexpr int NW_SH = 32768;   // node_W  256x128
constexpr int WC_SH = 16384;   // WcEt    128x128
constexpr int GF_SH = 65536;   // gfcn    128x512
constexpr int OFF_NWH = 0;
constexpr int OFF_NWL = NW_SH;
constexpr int OFF_WCH = 2 * NW_SH;
constexpr int OFF_WCL = 2 * NW_SH + WC_SH;
constexpr int OFF_GFH = 2 * NW_SH + 2 * WC_SH;
constexpr int OFF_GFL = 2 * NW_SH + 2 * WC_SH + GF_SH;
constexpr size_t OFF_BIAS_BYTES = (size_t)(2 * NW_SH + 2 * WC_SH + 2 * GF_SH) * 2; // 458752
constexpr size_t WS_NEED = OFF_BIAS_BYTES + 6 * 128 * 4;                            // ~462 KB

// ---- setup: pack weights into MFMA fragment layout (hi/lo bf16 planes) ------
__global__ __launch_bounds__(256) void setup_kernel(
    const float* __restrict__ node_W, const float* __restrict__ conv_W,
    const float* __restrict__ gfcn_W, const float* __restrict__ role_emb,
    const float* __restrict__ conv_b, const float* __restrict__ bn_gamma,
    const float* __restrict__ bn_beta, const float* __restrict__ bn_mean,
    const float* __restrict__ bn_var, short* __restrict__ wsS,
    float* __restrict__ bias_af) {
  int idx = blockIdx.x * 256 + threadIdx.x;
  int stride = gridDim.x * 256;
  for (int i = idx; i < 115456; i += stride) {
    if (i < 114688) {
      int j = i & 7, lane = (i >> 3) & 63;
      int kq = ((lane >> 4) & 3) * 8 + j, n16 = lane & 15;
      float val;
      short *ph, *pl;
      int loc;
      if (i < NW_SH) {
        loc = i;
        int f = i >> 9, kf = f & 7, nfr = f >> 3;
        int k = kf * 32 + kq, n = nfr * 16 + n16;
        val = node_W[k * 128 + n];
        ph = wsS + OFF_NWH; pl = wsS + OFF_NWL;
      } else if (i < NW_SH + WC_SH) {
        loc = i - NW_SH;
        int f = loc >> 9, kf = f & 3, nfr = f >> 2;
        int k = kf * 32 + kq, n = nfr * 16 + n16;
        float s = bn_gamma[n] * rsqrtf(bn_var[n] + 1e-5f);
        val = s * conv_W[n * 256 + 128 + k];     // WcEt[e=k][f=n]
        ph = wsS + OFF_WCH; pl = wsS + OFF_WCL;
      } else {
        loc = i - NW_SH - WC_SH;
        int f = loc >> 9, kf = f & 3, nfr = f >> 2;   // nfr 0..31
        int k = kf * 32 + kq, n = nfr * 16 + n16;     // n 0..511
        val = (n < 256) ? gfcn_W[k * 256 + n]
                        : gfcn_W[(128 + k) * 256 + (n - 256)];
        ph = wsS + OFF_GFH; pl = wsS + OFF_GFL;
      }
      short h, l;
      split2(val, h, l);
      ph[loc] = h; pl[loc] = l;
    } else {
      int loc = i - 114688;
      int a = loc >> 7, fc = loc & 127;
      int role = (a == 5) ? 6 : a;   // ROLES = {0,1,2,3,4,6}
      float s = bn_gamma[fc] * rsqrtf(bn_var[fc] + 1e-5f);
      float dot = 0.f;
      for (int e = 0; e < 128; ++e)
        dot = fmaf(role_emb[role * 128 + e], conv_W[fc * 256 + e], dot);
      bias_af[loc] = s * (dot + conv_b[fc] - bn_mean[fc]) + bn_beta[fc];
    }
  }
}

// ---- fused2: B (2 batches through 32KB stage) + C + D; 80KB LDS, 2 blk/CU ---
__global__ __launch_bounds__(512) void fused2_kernel(
    const int* __restrict__ a_ids, const int* __restrict__ b_ids,
    const int* __restrict__ c_ids, const int* __restrict__ event_ids,
    const float* __restrict__ nf, const float* __restrict__ ent,
    const float* __restrict__ node_b, const float* __restrict__ cond,
    const float* __restrict__ text, const float* __restrict__ gfcn_b,
    const short* __restrict__ wsS, const float* __restrict__ bias_af,
    float* __restrict__ out) {
  __shared__ __align__(16) unsigned char smem[81920];
  short* lds_hi = (short*)smem;                 // 96x128 bf16 hi plane
  short* lds_lo = (short*)(smem + 24576);       // lo plane
  unsigned char* stage = smem + 49152;          // 32KB: 2 a x 16 rows x 1KB
  float* umin_s = (float*)smem;                 // overlay after planes dead
  constexpr int OV = 260;

  const int t = threadIdx.x;
  const int wv = t >> 6, lane = t & 63;
  const int r15 = lane & 15, q = lane >> 4;
  const int tile = blockIdx.x;
  const int b0 = tile * 16;

  const bf16x8* nwh = (const bf16x8*)(wsS + OFF_NWH);
  const bf16x8* nwl = (const bf16x8*)(wsS + OFF_NWL);
  const bf16x8* wch = (const bf16x8*)(wsS + OFF_WCH);
  const bf16x8* wcl = (const bf16x8*)(wsS + OFF_WCL);
  const bf16x8* gfh = (const bf16x8*)(wsS + OFF_GFH);
  const bf16x8* gfl = (const bf16x8*)(wsS + OFF_GFL);

  // ids for all 4 columns at lane r15 (stack order a,event,b,c)
  int id0 = a_ids[b0 + r15], id1 = event_ids[b0 + r15];
  int id2 = b_ids[b0 + r15], id3 = c_ids[b0 + r15];

  // ---- STAGE(bb): wave wv stages rows {2wv, 2wv+1} of both a's in batch -----
  // LDS slot l of row rr holds global col16 (l ^ (rr&7)); 1 inst = 1KB row.
  auto STAGE = [&](int bb) {
    #pragma unroll
    for (int i = 0; i < 4; ++i) {
      int aL = i >> 1;                        // 0..1 within batch
      int rr = wv * 2 + (i & 1);              // 0..15
      int a = bb * 2 + aL;
      int ida = (a == 0) ? __shfl(id0, rr) : (a == 1) ? __shfl(id1, rr)
              : (a == 2) ? __shfl(id2, rr) : __shfl(id3, rr);
      int c16 = lane ^ (rr & 7);              // inverse-swizzled source slot
      const float* gp = nf + (size_t)ida * 256 + c16 * 4;
      __builtin_amdgcn_global_load_lds(
          (const __attribute__((address_space(1))) unsigned int*)(const void*)gp,
          (__attribute__((address_space(3))) unsigned int*)(void*)
              (stage + (aL * 16 + rr) * 1024),
          16, 0, 0);
    }
  };

  // ---- BCOMP(bb): wave (aL=wv>>2, nq=wv&3) computes n8 pair over full K -----
  auto BCOMP = [&](int bb) {
    int aL = wv >> 2, nq = wv & 3;
    int a = bb * 2 + aL;
    int idm = (a == 0) ? id0 : (a == 1) ? id1 : (a == 2) ? id2 : id3;
    float ev[8];
    #pragma unroll
    for (int j2 = 0; j2 < 2; ++j2) {
      int n8 = nq * 2 + j2;
      #pragma unroll
      for (int rg = 0; rg < 4; ++rg)
        ev[j2 * 4 + rg] =
            ent[(size_t)__shfl(idm, q * 4 + rg) * 128 + n8 * 16 + r15];
    }
    __builtin_amdgcn_sched_barrier(0);
    f32x4 acc[2];
    acc[0] = (f32x4){0.f, 0.f, 0.f, 0.f};
    acc[1] = (f32x4){0.f, 0.f, 0.f, 0.f};
    const unsigned char* base = stage + aL * 16384 + r15 * 1024;
    #pragma unroll
    for (int ks = 0; ks < 8; ++ks) {
      int c = ks * 8 + q * 2;
      float4 f0 = *(const float4*)(base + ((c ^ (r15 & 7)) * 16));
      float4 f1 = *(const float4*)(base + (((c + 1) ^ (r15 & 7)) * 16));
      bf16x8 Fh, Fl;
      #pragma unroll
      for (int j = 0; j < 4; ++j) {
        short h, l;
        split2(f0[j], h, l); Fh[j] = h; Fl[j] = l;
        split2(f1[j], h, l); Fh[4 + j] = h; Fl[4 + j] = l;
      }
      #pragma unroll
      for (int j2 = 0; j2 < 2; ++j2) {
        int n8 = nq * 2 + j2;
        bf16x8 bh = nwh[(n8 * 8 + ks) * 64 + lane];
        bf16x8 bl = nwl[(n8 * 8 + ks) * 64 + lane];
        acc[j2] = MFMA16(Fh, bh, acc[j2], 0, 0, 0);
        acc[j2] = MFMA16(Fl, bh, acc[j2], 0, 0, 0);
        acc[j2] = MFMA16(Fh, bl, acc[j2], 0, 0, 0);
      }
    }
    #pragma unroll
    for (int j2 = 0; j2 < 2; ++j2) {
      int n8 = nq * 2 + j2;
      int col = n8 * 16 + r15;
      float nb = node_b[col];
      #pragma unroll
      for (int rg = 0; rg < 4; ++rg) {
        float v = ev[j2 * 4 + rg] + fmaxf(acc[j2][rg] + nb, 0.f);
        short h, l; split2(v, h, l);
        int row = a * 16 + q * 4 + rg;
        int si = row * 128 + (col ^ ((row & 7) << 3));
        lds_hi[si] = h; lds_lo[si] = l;
      }
    }
  };

  // ---- Phase B ----
  STAGE(0);
  __builtin_amdgcn_sched_barrier(0);
  // cond/text rows (a=4,5) -> plane rows 64..95 (overlaps batch-0 stage)
  #pragma unroll
  for (int j = 0; j < 8; ++j) {
    int i = j * 512 + t;
    int arr = i >> 11, rem = i & 2047, r = rem >> 7, e = rem & 127;
    const float* src = arr ? text : cond;
    float v = src[(size_t)(b0 + r) * 128 + e];
    short h, l;
    split2(v, h, l);
    int row = (4 + arr) * 16 + r;
    int si = row * 128 + (e ^ ((row & 7) << 3));
    lds_hi[si] = h; lds_lo[si] = l;
  }
  asm volatile("s_waitcnt vmcnt(0)" ::: "memory");
  __builtin_amdgcn_sched_barrier(0);
  __syncthreads();
  BCOMP(0);
  __syncthreads();          // batch-0 stage reads done before overwrite
  STAGE(1);
  asm volatile("s_waitcnt vmcnt(0)" ::: "memory");
  __builtin_amdgcn_sched_barrier(0);
  __syncthreads();
  BCOMP(1);
  __syncthreads();          // vals rows 0..63 + cond/text 64..95 in planes

  // ---- Stage C: x = relu(vals @ WcEt + bias_af); wave owns n-frag wv --------
  {
    f32x4 xacc[6];
    #pragma unroll
    for (int a = 0; a < 6; ++a) xacc[a] = (f32x4){0.f, 0.f, 0.f, 0.f};
    #pragma unroll
    for (int ks = 0; ks < 4; ++ks) {
      int k0 = ks * 32 + q * 8;
      bf16x8 bh = wch[(wv * 4 + ks) * 64 + lane];
      bf16x8 bl = wcl[(wv * 4 + ks) * 64 + lane];
      #pragma unroll
      for (int ha = 0; ha < 2; ++ha) {
        bf16x8 ah[3], al[3];
        #pragma unroll
        for (int j = 0; j < 3; ++j) {
          int a = ha * 3 + j;
          int row = a * 16 + r15;
          int si = row * 128 + (k0 ^ ((row & 7) << 3));
          ah[j] = *(const bf16x8*)&lds_hi[si];
          al[j] = *(const bf16x8*)&lds_lo[si];
        }
        __builtin_amdgcn_s_setprio(1);
        #pragma unroll
        for (int j = 0; j < 3; ++j) {
          int a = ha * 3 + j;
          xacc[a] = MFMA16(ah[j], bh, xacc[a], 0, 0, 0);
          xacc[a] = MFMA16(al[j], bh, xacc[a], 0, 0, 0);
          xacc[a] = MFMA16(ah[j], bl, xacc[a], 0, 0, 0);
        }
        __builtin_amdgcn_s_setprio(0);
      }
    }
    __syncthreads();   // all plane reads done before x overwrites
    #pragma unroll
    for (int a = 0; a < 6; ++a) {
      int col = wv * 16 + r15;
      float bv = bias_af[a * 128 + col];
      #pragma unroll
      for (int rg = 0; rg < 4; ++rg) {
        float v = fmaxf(xacc[a][rg] + bv, 0.f);
        short h, l; split2(v, h, l);
        int row = a * 16 + q * 4 + rg;
        int si = row * 128 + (col ^ ((row & 7) << 3));
        lds_hi[si] = h; lds_lo[si] = l;
      }
    }
  }
  __syncthreads();

  // ---- Stage D: u/v = x @ gfcn; acc[6][4] merged, A-frag reused 12x ---------
  f32x4 acc[6][4];
  #pragma unroll
  for (int a = 0; a < 6; ++a)
    #pragma unroll
    for (int jn = 0; jn < 4; ++jn) acc[a][jn] = (f32x4){0.f, 0.f, 0.f, 0.f};
  #pragma unroll
  for (int ks = 0; ks < 4; ++ks) {
    int k0 = ks * 32 + q * 8;
    bf16x8 bh[4], bl[4];
    #pragma unroll
    for (int jn = 0; jn < 4; ++jn) {
      int nfg = wv * 4 + jn;
      bh[jn] = gfh[(nfg * 4 + ks) * 64 + lane];
      bl[jn] = gfl[(nfg * 4 + ks) * 64 + lane];
    }
    #pragma unroll
    for (int ha = 0; ha < 2; ++ha) {
      bf16x8 ah[3], al[3];
      #pragma unroll
      for (int j = 0; j < 3; ++j) {
        int row = (ha * 3 + j) * 16 + r15;
        int si = row * 128 + (k0 ^ ((row & 7) << 3));
        ah[j] = *(const bf16x8*)&lds_hi[si];
        al[j] = *(const bf16x8*)&lds_lo[si];
      }
      __builtin_amdgcn_s_setprio(1);
      #pragma unroll
      for (int jn = 0; jn < 4; ++jn) {
        #pragma unroll
        for (int j = 0; j < 3; ++j) {
          int a = ha * 3 + j;
          acc[a][jn] = MFMA16(ah[j], bh[jn], acc[a][jn], 0, 0, 0);
          acc[a][jn] = MFMA16(al[j], bh[jn], acc[a][jn], 0, 0, 0);
          acc[a][jn] = MFMA16(ah[j], bl[jn], acc[a][jn], 0, 0, 0);
        }
      }
      __builtin_amdgcn_s_setprio(0);
    }
  }
  f32x4 mreg[4];
  #pragma unroll
  for (int jn = 0; jn < 4; ++jn) {
    #pragma unroll
    for (int rg = 0; rg < 4; ++rg) {
      float mm = acc[0][jn][rg];
      #pragma unroll
      for (int a = 1; a < 6; ++a) mm = fminf(mm, acc[a][jn][rg]);
      mreg[jn][rg] = mm;
    }
  }
  __syncthreads();   // all x reads done; planes now dead

  if (wv < 4) {      // u waves: write umin to overlay
    #pragma unroll
    for (int j = 0; j < 4; ++j) {
      int colg = wv * 64 + j * 16 + r15;
      #pragma unroll
      for (int rg = 0; rg < 4; ++rg)
        umin_s[(q * 4 + rg) * OV + colg] = mreg[j][rg];
    }
  }
  __syncthreads();
  if (wv >= 4) {     // v waves: combine in-reg vmin with LDS umin, write out
    #pragma unroll
    for (int j = 0; j < 4; ++j) {
      int g = (wv - 4) * 64 + j * 16 + r15;
      float gbv = gfcn_b[g];
      #pragma unroll
      for (int rg = 0; rg < 4; ++rg) {
        int r = q * 4 + rg;
        out[(size_t)(b0 + r) * 256 + g] =
            fmaxf(umin_s[r * OV + g] + mreg[j][rg] + gbv, 0.f);
      }
    }
  }
}

// ---- fallback: fused (R5 structure, no min-wave bound) ----------------------
__global__ __launch_bounds__(256) void fused_fallback(
    const int* __restrict__ a_ids, const int* __restrict__ b_ids,
    const int* __restrict__ c_ids, const int* __restrict__ event_ids,
    const float* __restrict__ nf, const float* __restrict__ cond,
    const float* __restrict__ text, const float* __restrict__ ent,
    const float* __restrict__ node_b, const float* __restrict__ gfcn_b,
    const short* __restrict__ wsS, const float* __restrict__ bias_af,
    float* __restrict__ out) {
  __shared__ __align__(16) unsigned char smem[49152];
  short* lds_hi = (short*)smem;
  short* lds_lo = (short*)(smem + 24576);
  float* umin_s = (float*)smem;
  float* vmin_s = (float*)(smem + 16640);
  constexpr int OV = 260;

  const int t = threadIdx.x;
  const int wv = t >> 6, lane = t & 63;
  const int r15 = lane & 15, q = lane >> 4;
  const int b0 = blockIdx.x * 16;

  const bf16x8* nwh = (const bf16x8*)(wsS + OFF_NWH);
  const bf16x8* nwl = (const bf16x8*)(wsS + OFF_NWL);
  const bf16x8* wch = (const bf16x8*)(wsS + OFF_WCH);
  const bf16x8* wcl = (const bf16x8*)(wsS + OFF_WCL);
  const bf16x8* gfh = (const bf16x8*)(wsS + OFF_GFH);
  const bf16x8* gfl = (const bf16x8*)(wsS + OFF_GFL);

  const int* pw = (wv == 0) ? a_ids : (wv == 1) ? event_ids
                : (wv == 2) ? b_ids : c_ids;
  int my_id = pw[b0 + r15];
  int eid[4];
  #pragma unroll
  for (int rg = 0; rg < 4; ++rg) eid[rg] = pw[b0 + q * 4 + rg];
  const float* arow = nf + (size_t)my_id * 256 + q * 8;

  float4 avA[8];
  #pragma unroll
  for (int ks = 0; ks < 4; ++ks) {
    avA[2 * ks]     = *(const float4*)(arow + ks * 32);
    avA[2 * ks + 1] = *(const float4*)(arow + ks * 32 + 4);
  }
  #pragma unroll
  for (int j = 0; j < 16; ++j) {
    int i = j * 256 + t;
    int arr = i >> 11, rem = i & 2047, r = rem >> 7, e = rem & 127;
    const float* src = arr ? text : cond;
    float v = src[(size_t)(b0 + r) * 128 + e];
    short h, l;
    split2(v, h, l);
    int row = (4 + arr) * 16 + r;
    int si = row * 128 + (e ^ ((row & 7) << 3));
    lds_hi[si] = h; lds_lo[si] = l;
  }
  {
    f32x4 acc[8];
    #pragma unroll
    for (int n8 = 0; n8 < 8; ++n8) acc[n8] = (f32x4){0.f, 0.f, 0.f, 0.f};
    float4 avB[8];
    #pragma unroll
    for (int ks = 0; ks < 4; ++ks) {
      avB[2 * ks]     = *(const float4*)(arow + (4 + ks) * 32);
      avB[2 * ks + 1] = *(const float4*)(arow + (4 + ks) * 32 + 4);
    }
    #pragma unroll
    for (int ks = 0; ks < 8; ++ks) {
      bf16x8 ah, al;
      {
        float4 v0 = (ks < 4) ? avA[2 * ks] : avB[2 * (ks - 4)];
        float4 v1 = (ks < 4) ? avA[2 * ks + 1] : avB[2 * (ks - 4) + 1];
        #pragma unroll
        for (int j = 0; j < 4; ++j) {
          short h, l;
          split2(v0[j], h, l);
          ah[j] = h; al[j] = l;
          split2(v1[j], h, l);
          ah[4 + j] = h; al[4 + j] = l;
        }
      }
      #pragma unroll
      for (int n8 = 0; n8 < 8; ++n8) {
        bf16x8 bh = nwh[(n8 * 8 + ks) * 64 + lane];
        bf16x8 bl = nwl[(n8 * 8 + ks) * 64 + lane];
        acc[n8] = MFMA16(ah, bh, acc[n8], 0, 0, 0);
        acc[n8] = MFMA16(al, bh, acc[n8], 0, 0, 0);
        acc[n8] = MFMA16(ah, bl, acc[n8], 0, 0, 0);
      }
    }
    float ev[32];
    #pragma unroll
    for (int n8 = 0; n8 < 8; ++n8)
      #pragma unroll
      for (int rg = 0; rg < 4; ++rg)
        ev[n8 * 4 + rg] = ent[(size_t)eid[rg] * 128 + n8 * 16 + r15];
    #pragma unroll
    for (int n8 = 0; n8 < 8; ++n8) {
      int col = n8 * 16 + r15;
      float nb = node_b[col];
      #pragma unroll
      for (int rg = 0; rg < 4; ++rg) {
        float v = ev[n8 * 4 + rg] + fmaxf(acc[n8][rg] + nb, 0.f);
        short h, l; split2(v, h, l);
        int row = wv * 16 + q * 4 + rg;
        int si = row * 128 + (col ^ ((row & 7) << 3));
        lds_hi[si] = h; lds_lo[si] = l;
      }
    }
  }
  __syncthreads();
  {
    f32x4 xacc[6][2];
    #pragma unroll
    for (int a = 0; a < 6; ++a) {
      xacc[a][0] = (f32x4){0.f, 0.f, 0.f, 0.f};
      xacc[a][1] = (f32x4){0.f, 0.f, 0.f, 0.f};
    }
    #pragma unroll
    for (int ks = 0; ks < 4; ++ks) {
      int k0 = ks * 32 + q * 8;
      #pragma unroll
      for (int ha = 0; ha < 2; ++ha) {
        bf16x8 ah[3], al[3];
        #pragma unroll
        for (int j = 0; j < 3; ++j) {
          int row = (ha * 3 + j) * 16 + r15;
          int si = row * 128 + (k0 ^ ((row & 7) << 3));
          ah[j] = *(const bf16x8*)&lds_hi[si];
          al[j] = *(const bf16x8*)&lds_lo[si];
        }
        #pragma unroll
        for (int jn = 0; jn < 2; ++jn) {
          bf16x8 bh = wch[((wv * 2 + jn) * 4 + ks) * 64 + lane];
          bf16x8 bl = wcl[((wv * 2 + jn) * 4 + ks) * 64 + lane];
          #pragma unroll
          for (int j = 0; j < 3; ++j) {
            int a = ha * 3 + j;
            xacc[a][jn] = MFMA16(ah[j], bh, xacc[a][jn], 0, 0, 0);
            xacc[a][jn] = MFMA16(al[j], bh, xacc[a][jn], 0, 0, 0);
            xacc[a][jn] = MFMA16(ah[j], bl, xacc[a][jn], 0, 0, 0);
          }
        }
      }
    }
    __syncthreads();
    #pragma unroll
    for (int a = 0; a < 6; ++a) {
      #pragma unroll
      for (int jn = 0; jn < 2; ++jn) {
        int col = (wv * 2 + jn) * 16 + r15;
        float bv = bias_af[a * 128 + col];
        #pragma unroll
        for (int rg = 0; rg < 4; ++rg) {
          float v = fmaxf(xacc[a][jn][rg] + bv, 0.f);
          short h, l; split2(v, h, l);
          int row = a * 16 + q * 4 + rg;
          int si = row * 128 + (col ^ ((row & 7) << 3));
          lds_hi[si] = h; lds_lo[si] = l;
        }
      }
    }
  }
  __syncthreads();
  f32x4 mreg[8];
  #pragma unroll
  for (int grp = 0; grp < 4; ++grp) {
    f32x4 acc[6][2];
    #pragma unroll
    for (int a = 0; a < 6; ++a) {
      acc[a][0] = (f32x4){0.f, 0.f, 0.f, 0.f};
      acc[a][1] = (f32x4){0.f, 0.f, 0.f, 0.f};
    }
    #pragma unroll
    for (int ks = 0; ks < 4; ++ks) {
      int k0 = ks * 32 + q * 8;
      #pragma unroll
      for (int ha = 0; ha < 2; ++ha) {
        bf16x8 ah[3], al[3];
        #pragma unroll
        for (int j = 0; j < 3; ++j) {
          int row = (ha * 3 + j) * 16 + r15;
          int si = row * 128 + (k0 ^ ((row & 7) << 3));
          ah[j] = *(const bf16x8*)&lds_hi[si];
          al[j] = *(const bf16x8*)&lds_lo[si];
        }
        #pragma unroll
        for (int jn = 0; jn < 2; ++jn) {
          int nfg = wv * 8 + grp * 2 + jn;
          bf16x8 bh = gfh[(nfg * 4 + ks) * 64 + lane];
          bf16x8 bl = gfl[(nfg * 4 + ks) * 64 + lane];
          #pragma unroll
          for (int j = 0; j < 3; ++j) {
            int a = ha * 3 + j;
            acc[a][jn] = MFMA16(ah[j], bh, acc[a][jn], 0, 0, 0);
            acc[a][jn] = MFMA16(al[j], bh, acc[a][jn], 0, 0, 0);
            acc[a][jn] = MFMA16(ah[j], bl, acc[a][jn], 0, 0, 0);
          }
        }
      }
    }
    #pragma unroll
    for (int jn = 0; jn < 2; ++jn) {
      #pragma unroll
      for (int rg = 0; rg < 4; ++rg) {
        float mm = acc[0][jn][rg];
        #pragma unroll
        for (int a = 1; a < 6; ++a) mm = fminf(mm, acc[a][jn][rg]);
        mreg[grp * 2 + jn][rg] = mm;
      }
    }
  }
  __syncthreads();
  {
    float* dst = (wv >= 2) ? vmin_s : umin_s;
    int cbase = (wv & 1) * 128;
    #pragma unroll
    for (int j = 0; j < 8; ++j) {
      int colg = cbase + j * 16 + r15;
      #pragma unroll
      for (int rg = 0; rg < 4; ++rg)
        dst[(q * 4 + rg) * OV + colg] = mreg[j][rg];
    }
  }
  __syncthreads();
  #pragma unroll
  for (int j = 0; j < 16; ++j) {
    int i = j * 256 + t;
    int r = i >> 8, g = i & 255;
    out[(size_t)(b0 + r) * 256 + g] =
        fmaxf(umin_s[r * OV + g] + vmin_s[r * OV + g] + gfcn_b[g], 0.f);
  }
}

extern "C" void kernel_launch(void* const* d_in, const int* in_sizes, int n_in,
                              void* d_out, int out_size, void* d_ws, size_t ws_size,
                              hipStream_t stream) {
  const int* a_ids = (const int*)d_in[0];
  const int* b_ids = (const int*)d_in[1];
  const int* c_ids = (const int*)d_in[2];
  const int* event_ids = (const int*)d_in[3];
  const float* node_features = (const float*)d_in[4];
  const float* cond_rel = (const float*)d_in[5];
  const float* text = (const float*)d_in[6];
  const float* entity_emb = (const float*)d_in[7];
  const float* role_emb = (const float*)d_in[8];
  const float* node_W = (const float*)d_in[9];
  const float* node_b = (const float*)d_in[10];
  const float* conv_W = (const float*)d_in[11];
  const float* conv_b = (const float*)d_in[12];
  const float* bn_gamma = (const float*)d_in[13];
  const float* bn_beta = (const float*)d_in[14];
  const float* bn_mean = (const float*)d_in[15];
  const float* bn_var = (const float*)d_in[16];
  const float* gfcn_W = (const float*)d_in[17];
  const float* gfcn_b = (const float*)d_in[18];
  float* out = (float*)d_out;

  short* wsS = (short*)d_ws;
  float* bias_af = (float*)((char*)d_ws + OFF_BIAS_BYTES);
  const int B = in_sizes[0];   // 32768
  const int NT = B / 16;       // 2048

  setup_kernel<<<452, 256, 0, stream>>>(node_W, conv_W, gfcn_W, role_emb,
                                        conv_b, bn_gamma, bn_beta, bn_mean,
                                        bn_var, wsS, bias_af);
  if (ws_size >= WS_NEED) {
    fused2_kernel<<<NT, 512, 0, stream>>>(
        a_ids, b_ids, c_ids, event_ids, node_features, entity_emb, node_b,
        cond_rel, text, gfcn_b, wsS, bias_af, out);
  } else {
    fused_fallback<<<NT, 256, 0, stream>>>(
        a_ids, b_ids, c_ids, event_ids, node_features, cond_rel, text,
        entity_emb, node_b, gfcn_b, wsS, bias_af, out);
  }
}